// Round 4
// baseline (1203.439 us; speedup 1.0000x reference)
//
#include <hip/hip_runtime.h>
#include <cstddef>

#define B_  8
#define C_  256
#define H_  64
#define W_  64
#define HW_ 4096
#define NG_ 256   // 16x16 global tokens

typedef unsigned short u16;
typedef __attribute__((ext_vector_type(8))) short short8;   // 8 bf16 = 4 VGPRs
typedef __attribute__((ext_vector_type(4))) float f32x4;

__device__ __forceinline__ float sigm(float v) { return 1.f / (1.f + expf(-v)); }

__device__ __forceinline__ u16 f2bf(float f) {
    union { float f; unsigned u; } x; x.f = f;
    unsigned r = x.u + 0x7fff + ((x.u >> 16) & 1);   // RNE
    return (u16)(r >> 16);
}
__device__ __forceinline__ float bf2f(u16 h) {
    union { unsigned u; float f; } x; x.u = ((unsigned)h) << 16;
    return x.f;
}

// ---------------------------------------------------------------------------
// Pre-transpose + bf16-convert the 14 weight seg-matrices:
// Wpre[s][n][k] = bf16(Wsrc[rowoff+k][n]).  grid (8, 8, 14), block (32,8)
// seg order: 0 Wt | 1 Wf | 2 Ww | 3 Wo | 4-6 Wr | 7-9 Wgi | 10 Wl | 11-12 Wlf | 13 Wout
// ---------------------------------------------------------------------------
__global__ __launch_bounds__(256) void prepw_k(
    const float* __restrict__ Wt, const float* __restrict__ Wf, const float* __restrict__ Ww,
    const float* __restrict__ Wo, const float* __restrict__ Wr, const float* __restrict__ Wgi,
    const float* __restrict__ Wl, const float* __restrict__ Wlf, const float* __restrict__ Wout,
    u16* __restrict__ Wpre)
{
    int s = blockIdx.z;
    const float* Wsrc; int rowoff = 0;
    switch (s) {
        case 0: Wsrc = Wt; break;
        case 1: Wsrc = Wf; break;
        case 2: Wsrc = Ww; break;
        case 3: Wsrc = Wo; break;
        case 4: case 5: case 6: Wsrc = Wr;  rowoff = (s - 4) * 256; break;
        case 7: case 8: case 9: Wsrc = Wgi; rowoff = (s - 7) * 256; break;
        case 10: Wsrc = Wl; break;
        case 11: case 12: Wsrc = Wlf; rowoff = (s - 11) * 256; break;
        default: Wsrc = Wout; break;
    }
    __shared__ float t[32][33];
    int k0 = blockIdx.y * 32, n0 = blockIdx.x * 32;
    int tx = threadIdx.x, ty = threadIdx.y;
#pragma unroll
    for (int i = 0; i < 32; i += 8)
        t[ty + i][tx] = Wsrc[(size_t)(rowoff + k0 + ty + i) * 256 + n0 + tx];
    __syncthreads();
    u16* op = Wpre + (size_t)s * 65536;
#pragma unroll
    for (int i = 0; i < 32; i += 8)
        op[(size_t)(n0 + ty + i) * 256 + k0 + tx] = f2bf(t[tx][ty + i]);
}

// ---------------------------------------------------------------------------
// bf16 MFMA GEMM with fused epilogues.
// out[M,256] = sum_seg A_seg[M,256](bf16) @ W_seg (pre-transposed bf16 [n][k])
// Tile 64(m) x 128(n), 256 threads = 4 waves; wave = 32m x 64n via 2x4 mfma tiles.
// Epilogue modes:
//  0: out = D + bias[n]                              (fp32)
//  1: out = D + bias + pos[(m%NTOK)*256+n]; out2 = bf16(out)
//  2: out = D + bias[(m/NTOK)*256+n]                 (per-batch gate bias; dpre/wpre)
//  4: o-gate: Dn = D + bias[(m/NTOK)*256+n]; a=sigm(-aux0); g=sigm(aux1);
//     wout0=a; wout1=(1-a)*g*aux2; out=sigm(Dn)
//  5: rho: r=sigm(D+bias); y = r*bf(auxb0)+(1-r)*bf(auxb1); out=y; out2=bf16(y)
//  6: lam: l=sigm(D+bias); z = aux0 + l*bf(auxb0); out2=bf16(z)
//  7: v:   out2 = bf16(D+bias)
//  8: eta: e=sigm(D+bias); out2 = bf16(e*bf(auxb0)+(1-e)*bf(auxb1))
//  9: outproj: out[(b*256+n)*4096+hw] = aux0[same] + D + bias[n]  (transposed+residual)
// ---------------------------------------------------------------------------
#define LDK 72   // padded LDS row stride (144 B): gcd(36,32)=4 -> 2-way = free
__global__ __launch_bounds__(256, 4) void gemm_bf16(
    const u16* __restrict__ A0, const u16* __restrict__ A1, const u16* __restrict__ A2,
    int nseg, const u16* __restrict__ Wpre, const float* __restrict__ bias,
    const float* __restrict__ aux0, const float* __restrict__ aux1, const float* __restrict__ aux2,
    const u16* __restrict__ auxb0, const u16* __restrict__ auxb1,
    float* __restrict__ wout0, float* __restrict__ wout1,
    float* __restrict__ out, u16* __restrict__ out2, int NTOK, int mode)
{
    __shared__ u16 Asm[64 * LDK];
    __shared__ u16 Bsm[128 * LDK];
    const int tid = threadIdx.x;
    const int lane = tid & 63, wave = tid >> 6;
    const int wm = wave & 1, wn = wave >> 1;
    const int m0 = blockIdx.x * 64, n0 = blockIdx.y * 128;
    const int l15 = lane & 15, lq = lane >> 4;

    f32x4 acc[2][4] = {};

    const int rowA = tid >> 2, kA = (tid & 3) * 16;   // 64 rows, 2 x short8 each
    const int rowB = tid >> 1, kB = (tid & 1) * 32;   // 128 rows, 4 x short8 each

    for (int seg = 0; seg < nseg; ++seg) {
        const u16* __restrict__ A = (seg == 0) ? A0 : ((seg == 1) ? A1 : A2);
        const u16* arow = A + (size_t)(m0 + rowA) * 256 + kA;
        const u16* wrow = Wpre + (size_t)seg * 65536 + (size_t)(n0 + rowB) * 256 + kB;

        for (int k0 = 0; k0 < 256; k0 += 64) {
            *(short8*)(&Asm[rowA * LDK + kA])     = *(const short8*)(arow + k0);
            *(short8*)(&Asm[rowA * LDK + kA + 8]) = *(const short8*)(arow + k0 + 8);
#pragma unroll
            for (int c = 0; c < 4; ++c)
                *(short8*)(&Bsm[rowB * LDK + kB + c * 8]) =
                    *(const short8*)(wrow + k0 + c * 8);
            __syncthreads();

#pragma unroll
            for (int ks = 0; ks < 2; ++ks) {
                short8 af[2], bfr[4];
#pragma unroll
                for (int i = 0; i < 2; ++i)
                    af[i] = *(const short8*)(&Asm[(wm * 32 + i * 16 + l15) * LDK + ks * 32 + lq * 8]);
#pragma unroll
                for (int j = 0; j < 4; ++j)
                    bfr[j] = *(const short8*)(&Bsm[(wn * 64 + j * 16 + l15) * LDK + ks * 32 + lq * 8]);
#pragma unroll
                for (int i = 0; i < 2; ++i)
#pragma unroll
                    for (int j = 0; j < 4; ++j)
                        acc[i][j] = __builtin_amdgcn_mfma_f32_16x16x32_bf16(
                            af[i], bfr[j], acc[i][j], 0, 0, 0);
            }
            __syncthreads();
        }
    }

    // epilogue: lane holds D[m = lq*4+r][n = l15] per 16x16 tile
#pragma unroll
    for (int i = 0; i < 2; ++i) {
        int mbase = m0 + wm * 32 + i * 16 + lq * 4;
#pragma unroll
        for (int j = 0; j < 4; ++j) {
            int n = n0 + wn * 64 + j * 16 + l15;
            if (mode == 9) {
                int b9 = mbase >> 12, hw = mbase & 4095;
                size_t oi = ((size_t)b9 * 256 + n) * 4096 + hw;
                float bn = bias[n];
                float4 xr = *(const float4*)(aux0 + oi);
                float4 res;
                res.x = xr.x + acc[i][j][0] + bn;
                res.y = xr.y + acc[i][j][1] + bn;
                res.z = xr.z + acc[i][j][2] + bn;
                res.w = xr.w + acc[i][j][3] + bn;
                *(float4*)(out + oi) = res;
                continue;
            }
            float bn;
            if (mode == 2 || mode == 4) bn = bias[(size_t)(mbase / NTOK) * 256 + n];
            else                        bn = bias[n];
#pragma unroll
            for (int r = 0; r < 4; ++r) {
                int m = mbase + r;
                size_t idx = (size_t)m * 256 + n;
                float D = acc[i][j][r] + bn;
                if (mode == 0) {
                    out[idx] = D;
                } else if (mode == 1) {
                    float v = D + aux0[(size_t)(m % NTOK) * 256 + n];
                    out[idx] = v; out2[idx] = f2bf(v);
                } else if (mode == 2) {
                    out[idx] = D;
                } else if (mode == 4) {
                    float a = sigm(-aux0[idx]);
                    float g = sigm(aux1[idx]);
                    wout0[idx] = a;
                    wout1[idx] = (1.f - a) * g * aux2[idx];
                    out[idx] = sigm(D);
                } else if (mode == 5) {
                    float r_ = sigm(D);
                    float y = r_ * bf2f(auxb0[idx]) + (1.f - r_) * bf2f(auxb1[idx]);
                    out[idx] = y; out2[idx] = f2bf(y);
                } else if (mode == 6) {
                    float l = sigm(D);
                    float z = aux0[idx] + l * bf2f(auxb0[idx]);
                    out2[idx] = f2bf(z);
                } else if (mode == 7) {
                    out2[idx] = f2bf(D);
                } else { // 8
                    float e = sigm(D);
                    out2[idx] = f2bf(e * bf2f(auxb0[idx]) + (1.f - e) * bf2f(auxb1[idx]));
                }
            }
        }
    }
}

// ---------------------------------------------------------------------------
// Transpose x [B][C][HW] -> seq_bf [B][HW][C] bf16.
// grid (HW_/32, C_/32, B), block (32,8)
// ---------------------------------------------------------------------------
__global__ __launch_bounds__(256) void transpose_bf_k(const float* __restrict__ in,
                                                      u16* __restrict__ outb)
{
    __shared__ float t[32][33];
    int b = blockIdx.z;
    int r0 = blockIdx.y * 32, c0 = blockIdx.x * 32;   // r = channel, c = hw
    int tx = threadIdx.x, ty = threadIdx.y;
    const float* ip = in + (size_t)b * HW_ * C_;
    u16* op = outb + (size_t)b * HW_ * C_;
#pragma unroll
    for (int k = 0; k < 32; k += 8)
        t[ty + k][tx] = ip[(size_t)(r0 + ty + k) * HW_ + c0 + tx];
    __syncthreads();
#pragma unroll
    for (int k = 0; k < 32; k += 8)
        op[(size_t)(c0 + ty + k) * C_ + r0 + tx] = f2bf(t[tx][ty + k]);
}

// 4x4 avg pool x -> seqg_bf[B][256][C] bf16.  grid (B, C), block 256 = ghw
__global__ __launch_bounds__(256) void pool_k(const float* __restrict__ x, u16* __restrict__ seqg)
{
    int b = blockIdx.x, c = blockIdx.y, ghw = threadIdx.x;
    int gh = ghw >> 4, gw = ghw & 15;
    const float* xp = x + ((size_t)b * C_ + c) * HW_;
    float s = 0.f;
#pragma unroll
    for (int dy = 0; dy < 4; ++dy)
#pragma unroll
        for (int dx = 0; dx < 4; ++dx)
            s += xp[(gh * 4 + dy) * W_ + gw * 4 + dx];
    seqg[((size_t)b * NG_ + ghw) * C_ + c] = f2bf(s * (1.f / 16.f));
}

// pos_fine [1][256][32][32] -> posF[4096][256] fp32, half-pixel bilinear 2x
__global__ __launch_bounds__(256) void posfine_k(const float* __restrict__ pf, float* __restrict__ posF)
{
    int hw = blockIdx.x, c = threadIdx.x;
    int h = hw >> 6, w = hw & 63;
    float fy = h * 0.5f - 0.25f, fx = w * 0.5f - 0.25f;
    int y0 = (int)floorf(fy); float wy = fy - (float)y0;
    int x0 = (int)floorf(fx); float wx = fx - (float)x0;
    int y0c = min(max(y0, 0), 31), y1c = min(max(y0 + 1, 0), 31);
    int x0c = min(max(x0, 0), 31), x1c = min(max(x0 + 1, 0), 31);
    const float* p = pf + (size_t)c * 1024;
    float v = (1.f - wy) * ((1.f - wx) * p[y0c * 32 + x0c] + wx * p[y0c * 32 + x1c])
            +        wy  * ((1.f - wx) * p[y1c * 32 + x0c] + wx * p[y1c * 32 + x1c]);
    posF[(size_t)hw * C_ + c] = v;
}

// pos_glob -> posG[256][256] fp32: antialiased 2x downsample (4-tap triangle)
__global__ __launch_bounds__(256) void posglob_k(const float* __restrict__ pg, float* __restrict__ posG)
{
    int ghw = blockIdx.x, c = threadIdx.x;
    int gh = ghw >> 4, gw = ghw & 15;
    const float wt[4] = {0.125f, 0.375f, 0.375f, 0.125f};
    float wy[4], wx[4]; int jy[4], jx[4];
    float sy = 0.f, sx = 0.f;
#pragma unroll
    for (int k = 0; k < 4; ++k) {
        jy[k] = 2 * gh - 1 + k; jx[k] = 2 * gw - 1 + k;
        wy[k] = (jy[k] >= 0 && jy[k] < 32) ? wt[k] : 0.f; sy += wy[k];
        wx[k] = (jx[k] >= 0 && jx[k] < 32) ? wt[k] : 0.f; sx += wx[k];
    }
    const float* p = pg + (size_t)c * 1024;
    float acc = 0.f;
#pragma unroll
    for (int ky = 0; ky < 4; ++ky) {
        if (wy[ky] == 0.f) continue;
        float row = 0.f;
#pragma unroll
        for (int kx = 0; kx < 4; ++kx)
            if (wx[kx] != 0.f) row += wx[kx] * p[jy[ky] * 32 + jx[kx]];
        acc += wy[ky] * row;
    }
    posG[(size_t)ghw * C_ + c] = acc / (sy * sx);
}

// y_g[B][256][C] fp32 -> ygs_bf[B][4096][C] bf16: half-pixel bilinear 4x up
__global__ __launch_bounds__(256) void upsample_k(const float* __restrict__ yg, u16* __restrict__ ygs)
{
    int b = blockIdx.x >> 12, hw = blockIdx.x & 4095, c = threadIdx.x;
    int h = hw >> 6, w = hw & 63;
    float fy = h * 0.25f - 0.375f, fx = w * 0.25f - 0.375f;
    int y0 = (int)floorf(fy); float wy = fy - (float)y0;
    int x0 = (int)floorf(fx); float wx = fx - (float)x0;
    int y0c = min(max(y0, 0), 15), y1c = min(max(y0 + 1, 0), 15);
    int x0c = min(max(x0, 0), 15), x1c = min(max(x0 + 1, 0), 15);
    const float* p = yg + (size_t)b * NG_ * C_ + c;
    float v = (1.f - wy) * ((1.f - wx) * p[(y0c * 16 + x0c) * C_] + wx * p[(y0c * 16 + x1c) * C_])
            +        wy  * ((1.f - wx) * p[(y1c * 16 + x0c) * C_] + wx * p[(y1c * 16 + x1c) * C_]);
    ygs[((size_t)b * HW_ + hw) * C_ + c] = f2bf(v);
}

// depthwise 3x3 SAME conv + bias, fused transpose: -> vseq_bf[B][HW][C] bf16
// grid (B*H), block 256 = channel
__global__ __launch_bounds__(256) void dwconv_t_k(const float* __restrict__ x,
                                                  const float* __restrict__ dww,
                                                  const float* __restrict__ dwb,
                                                  u16* __restrict__ vseq)
{
    int b = blockIdx.x >> 6, h = blockIdx.x & 63, c = threadIdx.x;
    const float* xp = x + ((size_t)b * C_ + c) * HW_;
    float w9[9];
#pragma unroll
    for (int k = 0; k < 9; ++k) w9[k] = dww[c * 9 + k];
    float bsv = dwb[c];
    u16* op = vseq + ((size_t)b * HW_ + h * 64) * C_ + c;
    for (int w = 0; w < 64; ++w) {
        float acc = bsv;
#pragma unroll
        for (int dy = 0; dy < 3; ++dy) {
            int hh = h + dy - 1;
            if (hh < 0 || hh > 63) continue;
#pragma unroll
            for (int dx = 0; dx < 3; ++dx) {
                int ww = w + dx - 1;
                if (ww < 0 || ww > 63) continue;
                acc += xp[hh * 64 + ww] * w9[dy * 3 + dx];
            }
        }
        op[(size_t)w * C_] = f2bf(acc);
    }
}

// partial token-mean: grid (B, S), block 256=c
__global__ __launch_bounds__(256) void meanpart_k(const float* __restrict__ u, float* __restrict__ part,
                                                  int Ntok, int chunkLen)
{
    int b = blockIdx.x, s = blockIdx.y, c = threadIdx.x;
    float acc = 0.f;
    for (int i = 0; i < chunkLen; ++i) {
        int t = s * chunkLen + i;
        acc += u[((size_t)b * Ntok + t) * C_ + c];
    }
    part[((size_t)b * gridDim.y + s) * C_ + c] = acc;
}

// finish mean + LayerNorm over C.  grid (B), block 256
__global__ __launch_bounds__(256) void ln_k(const float* __restrict__ part, int S, float invN,
                                            const float* __restrict__ g, const float* __restrict__ bta,
                                            float* __restrict__ cout)
{
    __shared__ float red[256];
    int c = threadIdx.x, b = blockIdx.x;
    float v = 0.f;
    for (int s = 0; s < S; ++s) v += part[((size_t)b * S + s) * C_ + c];
    v *= invN;
    red[c] = v; __syncthreads();
    for (int st = 128; st > 0; st >>= 1) { if (c < st) red[c] += red[c + st]; __syncthreads(); }
    float m = red[0] * (1.f / 256.f);
    __syncthreads();
    float d = v - m;
    red[c] = d * d; __syncthreads();
    for (int st = 128; st > 0; st >>= 1) { if (c < st) red[c] += red[c + st]; __syncthreads(); }
    float var = red[0] * (1.f / 256.f);
    cout[(size_t)b * C_ + c] = d * rsqrtf(var + 1e-5f) * g[c] + bta[c];
}

// per-batch gate bias rows: cf[gate][b][n] = c[b] @ Wg[256:,:] + bg.  grid (B, 3), block 256
__global__ __launch_bounds__(256) void gatebias_k(const float* __restrict__ cvec,
    const float* __restrict__ Wf, const float* __restrict__ bf,
    const float* __restrict__ Ww, const float* __restrict__ bw,
    const float* __restrict__ Wo, const float* __restrict__ bo,
    float* __restrict__ outb)
{
    int n = threadIdx.x, b = blockIdx.x, gate = blockIdx.y;
    const float* Wm = (gate == 0) ? Wf : ((gate == 1) ? Ww : Wo);
    const float* bi = (gate == 0) ? bf : ((gate == 1) ? bw : bo);
    __shared__ float cs[256];
    cs[n] = cvec[(size_t)b * C_ + n];
    __syncthreads();
    float acc = bi[n];
    for (int k = 0; k < 256; ++k)
        acc += cs[k] * Wm[(size_t)(256 + k) * C_ + n];
    outb[((size_t)gate * B_ + b) * C_ + n] = acc;
}

// ---------------- chunked linear-recurrence scan -------------------------
__global__ __launch_bounds__(256) void scan_p1(const float* __restrict__ a, const float* __restrict__ bb,
                                               float* __restrict__ Ab, float* __restrict__ Bb,
                                               int Ntok, int chunkLen, int nchunk, int backward)
{
    int c = threadIdx.x;
    int chunk = blockIdx.x % nchunk;
    int b = blockIdx.x / nchunk;
    float sA = 1.f, sB = 0.f;
    for (int i = 0; i < chunkLen; ++i) {
        int tp = chunk * chunkLen + i;
        int t = backward ? (Ntok - 1 - tp) : tp;
        size_t idx = ((size_t)b * Ntok + t) * C_ + c;
        float av = a[idx];
        sB = av * sB + bb[idx];
        sA *= av;
    }
    size_t o = ((size_t)b * nchunk + chunk) * C_ + c;
    Ab[o] = sA; Bb[o] = sB;
}

__global__ __launch_bounds__(256) void scan_p2(const float* __restrict__ Ab, const float* __restrict__ Bb,
                                               float* __restrict__ Sb, int nchunk)
{
    int c = threadIdx.x, b = blockIdx.x;
    float s = 0.f;
    for (int ch = 0; ch < nchunk; ++ch) {
        size_t o = ((size_t)b * nchunk + ch) * C_ + c;
        Sb[o] = s;
        s = Ab[o] * s + Bb[o];
    }
}

// pass3: replay; emit y as fp32 (if yout) and/or bf16 (if ybf)
__global__ __launch_bounds__(256) void scan_p3(const float* __restrict__ a, const float* __restrict__ bb,
                                               const float* __restrict__ o_, const float* __restrict__ u,
                                               const float* __restrict__ Sb,
                                               float* __restrict__ yout, u16* __restrict__ ybf,
                                               int Ntok, int chunkLen, int nchunk, int backward)
{
    int c = threadIdx.x;
    int chunk = blockIdx.x % nchunk;
    int b = blockIdx.x / nchunk;
    float s = Sb[((size_t)b * nchunk + chunk) * C_ + c];
    for (int i = 0; i < chunkLen; ++i) {
        int tp = chunk * chunkLen + i;
        int t = backward ? (Ntok - 1 - tp) : tp;
        size_t idx = ((size_t)b * Ntok + t) * C_ + c;
        float av = a[idx];
        s = av * s + bb[idx];
        float ov = o_[idx];
        float y = ov * s + (1.f - ov) * u[idx];
        if (yout) yout[idx] = y;
        if (ybf)  ybf[idx] = f2bf(y);
    }
}

// ===========================================================================
extern "C" void kernel_launch(void* const* d_in, const int* in_sizes, int n_in,
                              void* d_out, int out_size, void* d_ws, size_t ws_size,
                              hipStream_t stream)
{
    const float* x        = (const float*)d_in[0];
    const float* Wt       = (const float*)d_in[1];
    const float* bt       = (const float*)d_in[2];
    const float* pos_fine = (const float*)d_in[3];
    const float* pos_glob = (const float*)d_in[4];
    const float* ln_g     = (const float*)d_in[5];
    const float* ln_b     = (const float*)d_in[6];
    const float* Wf       = (const float*)d_in[7];
    const float* bf       = (const float*)d_in[8];
    const float* Ww       = (const float*)d_in[9];
    const float* bw       = (const float*)d_in[10];
    const float* Wo       = (const float*)d_in[11];
    const float* bo       = (const float*)d_in[12];
    const float* Wr       = (const float*)d_in[13];
    const float* br       = (const float*)d_in[14];
    const float* Wgi      = (const float*)d_in[15];
    const float* bgi      = (const float*)d_in[16];
    const float* dww      = (const float*)d_in[17];
    const float* dwb      = (const float*)d_in[18];
    const float* Wl       = (const float*)d_in[19];
    const float* bl       = (const float*)d_in[20];
    const float* Wlf      = (const float*)d_in[21];
    const float* blf      = (const float*)d_in[22];
    const float* Wout     = (const float*)d_in[23];
    const float* bout     = (const float*)d_in[24];
    float* out = (float*)d_out;

    float* w = (float*)d_ws;
    const size_t BNC = (size_t)B_ * HW_ * C_;        // 8,388,608 elements
    // fp32 big buffers
    float* bu  = w + 0 * BNC;   // u fp32
    float* ba  = w + 1 * BNC;   // dpre -> a -> y(fp32)
    float* bbb = w + 2 * BNC;   // wpre -> bb
    float* bo_ = w + 3 * BNC;   // o
    // bf16 big buffers (each BNC u16 = BNC/2 floats of space)
    u16* bf1 = (u16*)(w + 4 * BNC);                  // seq_bf -> byf_bf -> z_bf
    u16* bf2 = bf1 + BNC;                            // bu_bf -> v_bf
    u16* bf3 = bf2 + BNC;                            // byb_bf -> vseq_bf -> uo_bf
    u16* bf4 = bf3 + BNC;                            // y_bf
    u16* bf5 = bf4 + BNC;                            // ygs_bf (long-lived)
    float* ext = w + 4 * BNC + 5 * (BNC / 2);
    float* posF = ext;  ext += (size_t)HW_ * C_;
    float* posG = ext;  ext += (size_t)NG_ * C_;
    float* part = ext;  ext += (size_t)B_ * 32 * C_;
    float* cln  = ext;  ext += (size_t)B_ * C_;
    float* cf   = ext;  ext += (size_t)3 * B_ * C_;
    float* ug   = ext;  ext += (size_t)B_ * NG_ * C_;
    float* dgp  = ext;  ext += (size_t)B_ * NG_ * C_;
    float* wgp  = ext;  ext += (size_t)B_ * NG_ * C_;
    float* ag   = ext;  ext += (size_t)B_ * NG_ * C_;
    float* bbg  = ext;  ext += (size_t)B_ * NG_ * C_;
    float* og   = ext;  ext += (size_t)B_ * NG_ * C_;
    float* ygt  = ext;  ext += (size_t)B_ * NG_ * C_;
    float* chA  = ext;  ext += (size_t)B_ * 64 * C_;
    float* chB  = ext;  ext += (size_t)B_ * 64 * C_;
    float* chS  = ext;  ext += (size_t)B_ * 64 * C_;
    u16* seqg_bf = (u16*)ext;  ext += (size_t)B_ * NG_ * C_ / 2;
    u16* ug_bf   = (u16*)ext;  ext += (size_t)B_ * NG_ * C_ / 2;
    u16* Wpre    = (u16*)ext;  // 14 * 65536 bf16 = 1.75 MiB

    const dim3 blk256(256);
    const dim3 blkT(32, 8);
    const dim3 gBig(B_ * HW_ / 64, 2);    // 512 x 2 = 1024 blocks
    const dim3 gSml(B_ * NG_ / 64, 2);    // 32 x 2 blocks
    const size_t WS = 65536;              // bf16 elems per weight seg
    // null sentinels: const for inputs, non-const for outputs
    const float *F0 = nullptr; const u16 *U0 = nullptr;
    float *FW = nullptr; u16 *UW = nullptr;

    // ---- weight prep ------------------------------------------------------
    prepw_k<<<dim3(8, 8, 14), blkT, 0, stream>>>(Wt, Wf, Ww, Wo, Wr, Wgi, Wl, Wlf, Wout, Wpre);

    // ---- fine: seq + u ----------------------------------------------------
    transpose_bf_k<<<dim3(HW_ / 32, C_ / 32, B_), blkT, 0, stream>>>(x, bf1);  // seq_bf
    posfine_k<<<HW_, blk256, 0, stream>>>(pos_fine, posF);
    gemm_bf16<<<gBig, blk256, 0, stream>>>(bf1, U0, U0, 1, Wpre + 0 * WS, bt,
        posF, F0, F0, U0, U0, FW, FW, bu, bf2, HW_, 1);          // u fp32 + bf16

    // ---- global branch ----------------------------------------------------
    pool_k<<<dim3(B_, C_), blk256, 0, stream>>>(x, seqg_bf);
    posglob_k<<<NG_, blk256, 0, stream>>>(pos_glob, posG);
    gemm_bf16<<<gSml, blk256, 0, stream>>>(seqg_bf, U0, U0, 1, Wpre + 0 * WS, bt,
        posG, F0, F0, U0, U0, FW, FW, ug, ug_bf, NG_, 1);
    meanpart_k<<<dim3(B_, 8), blk256, 0, stream>>>(ug, part, NG_, 32);
    ln_k<<<B_, blk256, 0, stream>>>(part, 8, 1.f / NG_, ln_g, ln_b, cln);
    gatebias_k<<<dim3(B_, 3), blk256, 0, stream>>>(cln, Wf, bf, Ww, bw, Wo, bo, cf);
    gemm_bf16<<<gSml, blk256, 0, stream>>>(ug_bf, U0, U0, 1, Wpre + 1 * WS, cf + 0 * B_ * C_,
        F0, F0, F0, U0, U0, FW, FW, dgp, UW, NG_, 2);
    gemm_bf16<<<gSml, blk256, 0, stream>>>(ug_bf, U0, U0, 1, Wpre + 2 * WS, cf + 1 * B_ * C_,
        F0, F0, F0, U0, U0, FW, FW, wgp, UW, NG_, 2);
    gemm_bf16<<<gSml, blk256, 0, stream>>>(ug_bf, U0, U0, 1, Wpre + 3 * WS, cf + 2 * B_ * C_,
        dgp, wgp, ug, U0, U0, ag, bbg, og, UW, NG_, 4);          // a, bb, o
    scan_p1<<<B_ * 16, blk256, 0, stream>>>(ag, bbg, chA, chB, NG_, 16, 16, 0);
    scan_p2<<<B_, blk256, 0, stream>>>(chA, chB, chS, 16);
    scan_p3<<<B_ * 16, blk256, 0, stream>>>(ag, bbg, og, ug, chS, ygt, UW, NG_, 16, 16, 0);
    upsample_k<<<B_ * HW_, blk256, 0, stream>>>(ygt, bf5);       // ygs_bf

    // ---- fine: gates + bidirectional scans -------------------------------
    meanpart_k<<<dim3(B_, 32), blk256, 0, stream>>>(bu, part, HW_, 128);
    ln_k<<<B_, blk256, 0, stream>>>(part, 32, 1.f / HW_, ln_g, ln_b, cln);
    gatebias_k<<<dim3(B_, 3), blk256, 0, stream>>>(cln, Wf, bf, Ww, bw, Wo, bo, cf);
    gemm_bf16<<<gBig, blk256, 0, stream>>>(bf2, U0, U0, 1, Wpre + 1 * WS, cf + 0 * B_ * C_,
        F0, F0, F0, U0, U0, FW, FW, ba, UW, HW_, 2);             // dpre
    gemm_bf16<<<gBig, blk256, 0, stream>>>(bf2, U0, U0, 1, Wpre + 2 * WS, cf + 1 * B_ * C_,
        F0, F0, F0, U0, U0, FW, FW, bbb, UW, HW_, 2);            // wpre
    gemm_bf16<<<gBig, blk256, 0, stream>>>(bf2, U0, U0, 1, Wpre + 3 * WS, cf + 2 * B_ * C_,
        ba, bbb, bu, U0, U0, ba, bbb, bo_, UW, HW_, 4);          // a->ba, bb->bbb, o->bo_
    // forward scan -> bf1 (byf_bf); backward -> bf3 (byb_bf)
    scan_p1<<<B_ * 64, blk256, 0, stream>>>(ba, bbb, chA, chB, HW_, 64, 64, 0);
    scan_p2<<<B_, blk256, 0, stream>>>(chA, chB, chS, 64);
    scan_p3<<<B_ * 64, blk256, 0, stream>>>(ba, bbb, bo_, bu, chS, FW, bf1, HW_, 64, 64, 0);
    scan_p1<<<B_ * 64, blk256, 0, stream>>>(ba, bbb, chA, chB, HW_, 64, 64, 1);
    scan_p2<<<B_, blk256, 0, stream>>>(chA, chB, chS, 64);
    scan_p3<<<B_ * 64, blk256, 0, stream>>>(ba, bbb, bo_, bu, chS, FW, bf3, HW_, 64, 64, 1);

    // ---- rho combine (fused) ----------------------------------------------
    gemm_bf16<<<gBig, blk256, 0, stream>>>(bf2, bf1, bf3, 3, Wpre + 4 * WS, br,
        F0, F0, F0, bf1, bf3, FW, FW, ba, bf4, HW_, 5);          // y -> ba(fp32) + bf4

    // ---- lam / z (fused) ---------------------------------------------------
    gemm_bf16<<<gBig, blk256, 0, stream>>>(bf4, bf5, bf2, 3, Wpre + 7 * WS, bgi,
        ba, F0, F0, bf5, U0, FW, FW, FW, bf1, HW_, 6);           // z -> bf1

    // ---- local depthwise branch -------------------------------------------
    dwconv_t_k<<<B_ * H_, blk256, 0, stream>>>(x, dww, dwb, bf3);           // vseq_bf
    gemm_bf16<<<gBig, blk256, 0, stream>>>(bf3, U0, U0, 1, Wpre + 10 * WS, bl,
        F0, F0, F0, U0, U0, FW, FW, FW, bf2, HW_, 7);            // v -> bf2
    gemm_bf16<<<gBig, blk256, 0, stream>>>(bf2, bf1, U0, 2, Wpre + 11 * WS, blf,
        F0, F0, F0, bf2, bf1, FW, FW, FW, bf3, HW_, 8);          // u_out -> bf3

    // ---- output projection + residual (fused transpose) -------------------
    gemm_bf16<<<gBig, blk256, 0, stream>>>(bf3, U0, U0, 1, Wpre + 13 * WS, bout,
        x, F0, F0, U0, U0, FW, FW, out, UW, HW_, 9);
}

// Round 5
// 833.019 us; speedup vs baseline: 1.4447x; 1.4447x over previous
//
#include <hip/hip_runtime.h>
#include <cstddef>

#define B_  8
#define C_  256
#define H_  64
#define W_  64
#define HW_ 4096
#define NG_ 256   // 16x16 global tokens

typedef unsigned short u16;
typedef __attribute__((ext_vector_type(8))) short short8;   // 8 bf16 = 4 VGPRs
typedef __attribute__((ext_vector_type(4))) float f32x4;

__device__ __forceinline__ float sigm(float v) { return 1.f / (1.f + expf(-v)); }

__device__ __forceinline__ u16 f2bf(float f) {
    union { float f; unsigned u; } x; x.f = f;
    unsigned r = x.u + 0x7fff + ((x.u >> 16) & 1);   // RNE
    return (u16)(r >> 16);
}
__device__ __forceinline__ float bf2f(u16 h) {
    union { unsigned u; float f; } x; x.u = ((unsigned)h) << 16;
    return x.f;
}

// ---------------------------------------------------------------------------
// Pre-transpose + bf16-convert the 14 weight seg-matrices:
// Wpre[s][n][k] = bf16(Wsrc[rowoff+k][n]).  grid (8, 8, 14), block (32,8)
// seg order: 0 Wt | 1 Wf | 2 Ww | 3 Wo | 4-6 Wr | 7-9 Wgi | 10 Wl | 11-12 Wlf | 13 Wout
// ---------------------------------------------------------------------------
__global__ __launch_bounds__(256) void prepw_k(
    const float* __restrict__ Wt, const float* __restrict__ Wf, const float* __restrict__ Ww,
    const float* __restrict__ Wo, const float* __restrict__ Wr, const float* __restrict__ Wgi,
    const float* __restrict__ Wl, const float* __restrict__ Wlf, const float* __restrict__ Wout,
    u16* __restrict__ Wpre)
{
    int s = blockIdx.z;
    const float* Wsrc; int rowoff = 0;
    switch (s) {
        case 0: Wsrc = Wt; break;
        case 1: Wsrc = Wf; break;
        case 2: Wsrc = Ww; break;
        case 3: Wsrc = Wo; break;
        case 4: case 5: case 6: Wsrc = Wr;  rowoff = (s - 4) * 256; break;
        case 7: case 8: case 9: Wsrc = Wgi; rowoff = (s - 7) * 256; break;
        case 10: Wsrc = Wl; break;
        case 11: case 12: Wsrc = Wlf; rowoff = (s - 11) * 256; break;
        default: Wsrc = Wout; break;
    }
    __shared__ float t[32][33];
    int k0 = blockIdx.y * 32, n0 = blockIdx.x * 32;
    int tx = threadIdx.x, ty = threadIdx.y;
#pragma unroll
    for (int i = 0; i < 32; i += 8)
        t[ty + i][tx] = Wsrc[(size_t)(rowoff + k0 + ty + i) * 256 + n0 + tx];
    __syncthreads();
    u16* op = Wpre + (size_t)s * 65536;
#pragma unroll
    for (int i = 0; i < 32; i += 8)
        op[(size_t)(n0 + ty + i) * 256 + k0 + tx] = f2bf(t[tx][ty + i]);
}

// ---------------------------------------------------------------------------
// bf16 MFMA GEMM with fused epilogues.
// out[M,256] = sum_seg A_seg[M,256](bf16) @ W_seg (pre-transposed bf16 [n][k])
// Tile 64(m) x 128(n), 256 threads = 4 waves; wave = 32m x 64n via 2x4 mfma tiles.
// Epilogue modes:
//  0: out = D + bias[n]                              (fp32)
//  1: out = D + bias + pos[(m%NTOK)*256+n]; out2 = bf16(out)
//  2: out = D + bias[(m/NTOK)*256+n]                 (per-batch gate bias; dpre/wpre)
//  4: o-gate: Dn = D + bias[(m/NTOK)*256+n]; a=sigm(-aux0); g=sigm(aux1);
//     wout0=a; wout1=(1-a)*g*aux2; out=sigm(Dn)
//  5: rho: r=sigm(D+bias); y = r*bf(auxb0)+(1-r)*bf(auxb1); out=y; out2=bf16(y)
//  6: lam: l=sigm(D+bias); z = aux0 + l*bf(auxb0); out2=bf16(z)
//  7: v:   out2 = bf16(D+bias)
//  8: eta: e=sigm(D+bias); out2 = bf16(e*bf(auxb0)+(1-e)*bf(auxb1))
//  9: outproj: out[(b*256+n)*4096+hw] = aux0[same] + D + bias[n]  (transposed+residual)
// ---------------------------------------------------------------------------
#define LDK 72   // padded LDS row stride (144 B): gcd(36,32)=4 -> 2-way = free
__global__ __launch_bounds__(256, 4) void gemm_bf16(
    const u16* __restrict__ A0, const u16* __restrict__ A1, const u16* __restrict__ A2,
    int nseg, const u16* __restrict__ Wpre, const float* __restrict__ bias,
    const float* __restrict__ aux0, const float* __restrict__ aux1, const float* __restrict__ aux2,
    const u16* __restrict__ auxb0, const u16* __restrict__ auxb1,
    float* __restrict__ wout0, float* __restrict__ wout1,
    float* __restrict__ out, u16* __restrict__ out2, int NTOK, int mode)
{
    __shared__ u16 Asm[64 * LDK];
    __shared__ u16 Bsm[128 * LDK];
    const int tid = threadIdx.x;
    const int lane = tid & 63, wave = tid >> 6;
    const int wm = wave & 1, wn = wave >> 1;
    const int m0 = blockIdx.x * 64, n0 = blockIdx.y * 128;
    const int l15 = lane & 15, lq = lane >> 4;

    f32x4 acc[2][4] = {};

    const int rowA = tid >> 2, kA = (tid & 3) * 16;   // 64 rows, 2 x short8 each
    const int rowB = tid >> 1, kB = (tid & 1) * 32;   // 128 rows, 4 x short8 each

    for (int seg = 0; seg < nseg; ++seg) {
        const u16* __restrict__ A = (seg == 0) ? A0 : ((seg == 1) ? A1 : A2);
        const u16* arow = A + (size_t)(m0 + rowA) * 256 + kA;
        const u16* wrow = Wpre + (size_t)seg * 65536 + (size_t)(n0 + rowB) * 256 + kB;

        for (int k0 = 0; k0 < 256; k0 += 64) {
            *(short8*)(&Asm[rowA * LDK + kA])     = *(const short8*)(arow + k0);
            *(short8*)(&Asm[rowA * LDK + kA + 8]) = *(const short8*)(arow + k0 + 8);
#pragma unroll
            for (int c = 0; c < 4; ++c)
                *(short8*)(&Bsm[rowB * LDK + kB + c * 8]) =
                    *(const short8*)(wrow + k0 + c * 8);
            __syncthreads();

#pragma unroll
            for (int ks = 0; ks < 2; ++ks) {
                short8 af[2], bfr[4];
#pragma unroll
                for (int i = 0; i < 2; ++i)
                    af[i] = *(const short8*)(&Asm[(wm * 32 + i * 16 + l15) * LDK + ks * 32 + lq * 8]);
#pragma unroll
                for (int j = 0; j < 4; ++j)
                    bfr[j] = *(const short8*)(&Bsm[(wn * 64 + j * 16 + l15) * LDK + ks * 32 + lq * 8]);
#pragma unroll
                for (int i = 0; i < 2; ++i)
#pragma unroll
                    for (int j = 0; j < 4; ++j)
                        acc[i][j] = __builtin_amdgcn_mfma_f32_16x16x32_bf16(
                            af[i], bfr[j], acc[i][j], 0, 0, 0);
            }
            __syncthreads();
        }
    }

    // epilogue: lane holds D[m = lq*4+r][n = l15] per 16x16 tile
#pragma unroll
    for (int i = 0; i < 2; ++i) {
        int mbase = m0 + wm * 32 + i * 16 + lq * 4;
#pragma unroll
        for (int j = 0; j < 4; ++j) {
            int n = n0 + wn * 64 + j * 16 + l15;
            if (mode == 9) {
                int b9 = mbase >> 12, hw = mbase & 4095;
                size_t oi = ((size_t)b9 * 256 + n) * 4096 + hw;
                float bn = bias[n];
                float4 xr = *(const float4*)(aux0 + oi);
                float4 res;
                res.x = xr.x + acc[i][j][0] + bn;
                res.y = xr.y + acc[i][j][1] + bn;
                res.z = xr.z + acc[i][j][2] + bn;
                res.w = xr.w + acc[i][j][3] + bn;
                *(float4*)(out + oi) = res;
                continue;
            }
            float bn;
            if (mode == 2 || mode == 4) bn = bias[(size_t)(mbase / NTOK) * 256 + n];
            else                        bn = bias[n];
#pragma unroll
            for (int r = 0; r < 4; ++r) {
                int m = mbase + r;
                size_t idx = (size_t)m * 256 + n;
                float D = acc[i][j][r] + bn;
                if (mode == 0) {
                    out[idx] = D;
                } else if (mode == 1) {
                    float v = D + aux0[(size_t)(m % NTOK) * 256 + n];
                    out[idx] = v; out2[idx] = f2bf(v);
                } else if (mode == 2) {
                    out[idx] = D;
                } else if (mode == 4) {
                    float a = sigm(-aux0[idx]);
                    float g = sigm(aux1[idx]);
                    wout0[idx] = a;
                    wout1[idx] = (1.f - a) * g * aux2[idx];
                    out[idx] = sigm(D);
                } else if (mode == 5) {
                    float r_ = sigm(D);
                    float y = r_ * bf2f(auxb0[idx]) + (1.f - r_) * bf2f(auxb1[idx]);
                    out[idx] = y; out2[idx] = f2bf(y);
                } else if (mode == 6) {
                    float l = sigm(D);
                    float z = aux0[idx] + l * bf2f(auxb0[idx]);
                    out2[idx] = f2bf(z);
                } else if (mode == 7) {
                    out2[idx] = f2bf(D);
                } else { // 8
                    float e = sigm(D);
                    out2[idx] = f2bf(e * bf2f(auxb0[idx]) + (1.f - e) * bf2f(auxb1[idx]));
                }
            }
        }
    }
}

// ---------------------------------------------------------------------------
// Transpose x [B][C][HW] fp32 -> seq_bf [B][HW][C] bf16.
// grid (HW_/32, C_/32, B), block (32,8)
// ---------------------------------------------------------------------------
__global__ __launch_bounds__(256) void transpose_bf_k(const float* __restrict__ in,
                                                      u16* __restrict__ outb)
{
    __shared__ float t[32][33];
    int b = blockIdx.z;
    int r0 = blockIdx.y * 32, c0 = blockIdx.x * 32;   // r = channel, c = hw
    int tx = threadIdx.x, ty = threadIdx.y;
    const float* ip = in + (size_t)b * HW_ * C_;
    u16* op = outb + (size_t)b * HW_ * C_;
#pragma unroll
    for (int k = 0; k < 32; k += 8)
        t[ty + k][tx] = ip[(size_t)(r0 + ty + k) * HW_ + c0 + tx];
    __syncthreads();
#pragma unroll
    for (int k = 0; k < 32; k += 8)
        op[(size_t)(c0 + ty + k) * C_ + r0 + tx] = f2bf(t[tx][ty + k]);
}

// 4x4 avg pool x -> seqg_bf[B][256][C] bf16.  grid (B, C), block 256 = ghw
__global__ __launch_bounds__(256) void pool_k(const float* __restrict__ x, u16* __restrict__ seqg)
{
    int b = blockIdx.x, c = blockIdx.y, ghw = threadIdx.x;
    int gh = ghw >> 4, gw = ghw & 15;
    const float* xp = x + ((size_t)b * C_ + c) * HW_;
    float s = 0.f;
#pragma unroll
    for (int dy = 0; dy < 4; ++dy)
#pragma unroll
        for (int dx = 0; dx < 4; ++dx)
            s += xp[(gh * 4 + dy) * W_ + gw * 4 + dx];
    seqg[((size_t)b * NG_ + ghw) * C_ + c] = f2bf(s * (1.f / 16.f));
}

// pos_fine [1][256][32][32] -> posF[4096][256] fp32, half-pixel bilinear 2x
__global__ __launch_bounds__(256) void posfine_k(const float* __restrict__ pf, float* __restrict__ posF)
{
    int hw = blockIdx.x, c = threadIdx.x;
    int h = hw >> 6, w = hw & 63;
    float fy = h * 0.5f - 0.25f, fx = w * 0.5f - 0.25f;
    int y0 = (int)floorf(fy); float wy = fy - (float)y0;
    int x0 = (int)floorf(fx); float wx = fx - (float)x0;
    int y0c = min(max(y0, 0), 31), y1c = min(max(y0 + 1, 0), 31);
    int x0c = min(max(x0, 0), 31), x1c = min(max(x0 + 1, 0), 31);
    const float* p = pf + (size_t)c * 1024;
    float v = (1.f - wy) * ((1.f - wx) * p[y0c * 32 + x0c] + wx * p[y0c * 32 + x1c])
            +        wy  * ((1.f - wx) * p[y1c * 32 + x0c] + wx * p[y1c * 32 + x1c]);
    posF[(size_t)hw * C_ + c] = v;
}

// pos_glob -> posG[256][256] fp32: antialiased 2x downsample (4-tap triangle)
__global__ __launch_bounds__(256) void posglob_k(const float* __restrict__ pg, float* __restrict__ posG)
{
    int ghw = blockIdx.x, c = threadIdx.x;
    int gh = ghw >> 4, gw = ghw & 15;
    const float wt[4] = {0.125f, 0.375f, 0.375f, 0.125f};
    float wy[4], wx[4]; int jy[4], jx[4];
    float sy = 0.f, sx = 0.f;
#pragma unroll
    for (int k = 0; k < 4; ++k) {
        jy[k] = 2 * gh - 1 + k; jx[k] = 2 * gw - 1 + k;
        wy[k] = (jy[k] >= 0 && jy[k] < 32) ? wt[k] : 0.f; sy += wy[k];
        wx[k] = (jx[k] >= 0 && jx[k] < 32) ? wt[k] : 0.f; sx += wx[k];
    }
    const float* p = pg + (size_t)c * 1024;
    float acc = 0.f;
#pragma unroll
    for (int ky = 0; ky < 4; ++ky) {
        if (wy[ky] == 0.f) continue;
        float row = 0.f;
#pragma unroll
        for (int kx = 0; kx < 4; ++kx)
            if (wx[kx] != 0.f) row += wx[kx] * p[jy[ky] * 32 + jx[kx]];
        acc += wy[ky] * row;
    }
    posG[(size_t)ghw * C_ + c] = acc / (sy * sx);
}

// y_g[B][256][C] fp32 -> ygs_bf[B][4096][C] bf16: half-pixel bilinear 4x up
__global__ __launch_bounds__(256) void upsample_k(const float* __restrict__ yg, u16* __restrict__ ygs)
{
    int b = blockIdx.x >> 12, hw = blockIdx.x & 4095, c = threadIdx.x;
    int h = hw >> 6, w = hw & 63;
    float fy = h * 0.25f - 0.375f, fx = w * 0.25f - 0.375f;
    int y0 = (int)floorf(fy); float wy = fy - (float)y0;
    int x0 = (int)floorf(fx); float wx = fx - (float)x0;
    int y0c = min(max(y0, 0), 15), y1c = min(max(y0 + 1, 0), 15);
    int x0c = min(max(x0, 0), 15), x1c = min(max(x0 + 1, 0), 15);
    const float* p = yg + (size_t)b * NG_ * C_ + c;
    float v = (1.f - wy) * ((1.f - wx) * p[(y0c * 16 + x0c) * C_] + wx * p[(y0c * 16 + x1c) * C_])
            +        wy  * ((1.f - wx) * p[(y1c * 16 + x0c) * C_] + wx * p[(y1c * 16 + x1c) * C_]);
    ygs[((size_t)b * HW_ + hw) * C_ + c] = f2bf(v);
}

// depthwise 3x3 SAME conv + bias -> vmap[B][C][HW] fp32 (coalesced along hw).
// grid (B*C, 16), block 256
__global__ __launch_bounds__(256) void dwconv_k(const float* __restrict__ x,
                                                const float* __restrict__ dww,
                                                const float* __restrict__ dwb,
                                                float* __restrict__ vmap)
{
    int bc = blockIdx.x;
    int hw = blockIdx.y * 256 + threadIdx.x;
    int c = bc & 255;
    int h = hw >> 6, w = hw & 63;
    const float* xp = x + (size_t)bc * HW_;
    const float* wp = dww + c * 9;
    float acc = dwb[c];
#pragma unroll
    for (int dy = 0; dy < 3; ++dy) {
        int hh = h + dy - 1;
        if (hh < 0 || hh > 63) continue;
#pragma unroll
        for (int dx = 0; dx < 3; ++dx) {
            int ww = w + dx - 1;
            if (ww < 0 || ww > 63) continue;
            acc += xp[hh * W_ + ww] * wp[dy * 3 + dx];
        }
    }
    vmap[(size_t)bc * HW_ + hw] = acc;
}

// partial token-mean: grid (B, S), block 256=c
__global__ __launch_bounds__(256) void meanpart_k(const float* __restrict__ u, float* __restrict__ part,
                                                  int Ntok, int chunkLen)
{
    int b = blockIdx.x, s = blockIdx.y, c = threadIdx.x;
    float acc = 0.f;
    for (int i = 0; i < chunkLen; ++i) {
        int t = s * chunkLen + i;
        acc += u[((size_t)b * Ntok + t) * C_ + c];
    }
    part[((size_t)b * gridDim.y + s) * C_ + c] = acc;
}

// finish mean + LayerNorm over C.  grid (B), block 256
__global__ __launch_bounds__(256) void ln_k(const float* __restrict__ part, int S, float invN,
                                            const float* __restrict__ g, const float* __restrict__ bta,
                                            float* __restrict__ cout)
{
    __shared__ float red[256];
    int c = threadIdx.x, b = blockIdx.x;
    float v = 0.f;
    for (int s = 0; s < S; ++s) v += part[((size_t)b * S + s) * C_ + c];
    v *= invN;
    red[c] = v; __syncthreads();
    for (int st = 128; st > 0; st >>= 1) { if (c < st) red[c] += red[c + st]; __syncthreads(); }
    float m = red[0] * (1.f / 256.f);
    __syncthreads();
    float d = v - m;
    red[c] = d * d; __syncthreads();
    for (int st = 128; st > 0; st >>= 1) { if (c < st) red[c] += red[c + st]; __syncthreads(); }
    float var = red[0] * (1.f / 256.f);
    cout[(size_t)b * C_ + c] = d * rsqrtf(var + 1e-5f) * g[c] + bta[c];
}

// per-batch gate bias rows: cf[gate][b][n] = c[b] @ Wg[256:,:] + bg.  grid (B, 3), block 256
__global__ __launch_bounds__(256) void gatebias_k(const float* __restrict__ cvec,
    const float* __restrict__ Wf, const float* __restrict__ bf,
    const float* __restrict__ Ww, const float* __restrict__ bw,
    const float* __restrict__ Wo, const float* __restrict__ bo,
    float* __restrict__ outb)
{
    int n = threadIdx.x, b = blockIdx.x, gate = blockIdx.y;
    const float* Wm = (gate == 0) ? Wf : ((gate == 1) ? Ww : Wo);
    const float* bi = (gate == 0) ? bf : ((gate == 1) ? bw : bo);
    __shared__ float cs[256];
    cs[n] = cvec[(size_t)b * C_ + n];
    __syncthreads();
    float acc = bi[n];
    for (int k = 0; k < 256; ++k)
        acc += cs[k] * Wm[(size_t)(256 + k) * C_ + n];
    outb[((size_t)gate * B_ + b) * C_ + n] = acc;
}

// ---------------- chunked linear-recurrence scan -------------------------
__global__ __launch_bounds__(256) void scan_p1(const float* __restrict__ a, const float* __restrict__ bb,
                                               float* __restrict__ Ab, float* __restrict__ Bb,
                                               int Ntok, int chunkLen, int nchunk, int backward)
{
    int c = threadIdx.x;
    int chunk = blockIdx.x % nchunk;
    int b = blockIdx.x / nchunk;
    float sA = 1.f, sB = 0.f;
    for (int i = 0; i < chunkLen; ++i) {
        int tp = chunk * chunkLen + i;
        int t = backward ? (Ntok - 1 - tp) : tp;
        size_t idx = ((size_t)b * Ntok + t) * C_ + c;
        float av = a[idx];
        sB = av * sB + bb[idx];
        sA *= av;
    }
    size_t o = ((size_t)b * nchunk + chunk) * C_ + c;
    Ab[o] = sA; Bb[o] = sB;
}

__global__ __launch_bounds__(256) void scan_p2(const float* __restrict__ Ab, const float* __restrict__ Bb,
                                               float* __restrict__ Sb, int nchunk)
{
    int c = threadIdx.x, b = blockIdx.x;
    float s = 0.f;
    for (int ch = 0; ch < nchunk; ++ch) {
        size_t o = ((size_t)b * nchunk + ch) * C_ + c;
        Sb[o] = s;
        s = Ab[o] * s + Bb[o];
    }
}

// pass3: replay; emit y as fp32 (if yout) and/or bf16 (if ybf)
__global__ __launch_bounds__(256) void scan_p3(const float* __restrict__ a, const float* __restrict__ bb,
                                               const float* __restrict__ o_, const float* __restrict__ u,
                                               const float* __restrict__ Sb,
                                               float* __restrict__ yout, u16* __restrict__ ybf,
                                               int Ntok, int chunkLen, int nchunk, int backward)
{
    int c = threadIdx.x;
    int chunk = blockIdx.x % nchunk;
    int b = blockIdx.x / nchunk;
    float s = Sb[((size_t)b * nchunk + chunk) * C_ + c];
    for (int i = 0; i < chunkLen; ++i) {
        int tp = chunk * chunkLen + i;
        int t = backward ? (Ntok - 1 - tp) : tp;
        size_t idx = ((size_t)b * Ntok + t) * C_ + c;
        float av = a[idx];
        s = av * s + bb[idx];
        float ov = o_[idx];
        float y = ov * s + (1.f - ov) * u[idx];
        if (yout) yout[idx] = y;
        if (ybf)  ybf[idx] = f2bf(y);
    }
}

// ===========================================================================
extern "C" void kernel_launch(void* const* d_in, const int* in_sizes, int n_in,
                              void* d_out, int out_size, void* d_ws, size_t ws_size,
                              hipStream_t stream)
{
    const float* x        = (const float*)d_in[0];
    const float* Wt       = (const float*)d_in[1];
    const float* bt       = (const float*)d_in[2];
    const float* pos_fine = (const float*)d_in[3];
    const float* pos_glob = (const float*)d_in[4];
    const float* ln_g     = (const float*)d_in[5];
    const float* ln_b     = (const float*)d_in[6];
    const float* Wf       = (const float*)d_in[7];
    const float* bf       = (const float*)d_in[8];
    const float* Ww       = (const float*)d_in[9];
    const float* bw       = (const float*)d_in[10];
    const float* Wo       = (const float*)d_in[11];
    const float* bo       = (const float*)d_in[12];
    const float* Wr       = (const float*)d_in[13];
    const float* br       = (const float*)d_in[14];
    const float* Wgi      = (const float*)d_in[15];
    const float* bgi      = (const float*)d_in[16];
    const float* dww      = (const float*)d_in[17];
    const float* dwb      = (const float*)d_in[18];
    const float* Wl       = (const float*)d_in[19];
    const float* bl       = (const float*)d_in[20];
    const float* Wlf      = (const float*)d_in[21];
    const float* blf      = (const float*)d_in[22];
    const float* Wout     = (const float*)d_in[23];
    const float* bout     = (const float*)d_in[24];
    float* out = (float*)d_out;

    float* w = (float*)d_ws;
    const size_t BNC = (size_t)B_ * HW_ * C_;        // 8,388,608 elements
    // fp32 big buffers
    float* bu  = w + 0 * BNC;   // u fp32 -> (after scans) vmap fp32
    float* ba  = w + 1 * BNC;   // dpre -> a -> y(fp32)
    float* bbb = w + 2 * BNC;   // wpre -> bb
    float* bo_ = w + 3 * BNC;   // o
    // bf16 big buffers (each BNC u16 = BNC/2 floats of space)
    u16* bf1 = (u16*)(w + 4 * BNC);                  // seq_bf -> byf_bf -> z_bf
    u16* bf2 = bf1 + BNC;                            // bu_bf -> v_bf
    u16* bf3 = bf2 + BNC;                            // byb_bf -> vseq_bf -> uo_bf
    u16* bf4 = bf3 + BNC;                            // y_bf
    u16* bf5 = bf4 + BNC;                            // ygs_bf (long-lived)
    float* ext = w + 4 * BNC + 5 * (BNC / 2);
    float* posF = ext;  ext += (size_t)HW_ * C_;
    float* posG = ext;  ext += (size_t)NG_ * C_;
    float* part = ext;  ext += (size_t)B_ * 32 * C_;
    float* cln  = ext;  ext += (size_t)B_ * C_;
    float* cf   = ext;  ext += (size_t)3 * B_ * C_;
    float* ug   = ext;  ext += (size_t)B_ * NG_ * C_;
    float* dgp  = ext;  ext += (size_t)B_ * NG_ * C_;
    float* wgp  = ext;  ext += (size_t)B_ * NG_ * C_;
    float* ag   = ext;  ext += (size_t)B_ * NG_ * C_;
    float* bbg  = ext;  ext += (size_t)B_ * NG_ * C_;
    float* og   = ext;  ext += (size_t)B_ * NG_ * C_;
    float* ygt  = ext;  ext += (size_t)B_ * NG_ * C_;
    float* chA  = ext;  ext += (size_t)B_ * 64 * C_;
    float* chB  = ext;  ext += (size_t)B_ * 64 * C_;
    float* chS  = ext;  ext += (size_t)B_ * 64 * C_;
    u16* seqg_bf = (u16*)ext;  ext += (size_t)B_ * NG_ * C_ / 2;
    u16* ug_bf   = (u16*)ext;  ext += (size_t)B_ * NG_ * C_ / 2;
    u16* Wpre    = (u16*)ext;  // 14 * 65536 bf16 = 1.75 MiB

    const dim3 blk256(256);
    const dim3 blkT(32, 8);
    const dim3 gBig(B_ * HW_ / 64, 2);    // 512 x 2 = 1024 blocks
    const dim3 gSml(B_ * NG_ / 64, 2);    // 32 x 2 blocks
    const size_t WS = 65536;              // bf16 elems per weight seg
    // null sentinels: const for inputs, non-const for outputs
    const float *F0 = nullptr; const u16 *U0 = nullptr;
    float *FW = nullptr; u16 *UW = nullptr;

    // ---- weight prep ------------------------------------------------------
    prepw_k<<<dim3(8, 8, 14), blkT, 0, stream>>>(Wt, Wf, Ww, Wo, Wr, Wgi, Wl, Wlf, Wout, Wpre);

    // ---- fine: seq + u ----------------------------------------------------
    transpose_bf_k<<<dim3(HW_ / 32, C_ / 32, B_), blkT, 0, stream>>>(x, bf1);  // seq_bf
    posfine_k<<<HW_, blk256, 0, stream>>>(pos_fine, posF);
    gemm_bf16<<<gBig, blk256, 0, stream>>>(bf1, U0, U0, 1, Wpre + 0 * WS, bt,
        posF, F0, F0, U0, U0, FW, FW, bu, bf2, HW_, 1);          // u fp32 + bf16

    // ---- global branch ----------------------------------------------------
    pool_k<<<dim3(B_, C_), blk256, 0, stream>>>(x, seqg_bf);
    posglob_k<<<NG_, blk256, 0, stream>>>(pos_glob, posG);
    gemm_bf16<<<gSml, blk256, 0, stream>>>(seqg_bf, U0, U0, 1, Wpre + 0 * WS, bt,
        posG, F0, F0, U0, U0, FW, FW, ug, ug_bf, NG_, 1);
    meanpart_k<<<dim3(B_, 8), blk256, 0, stream>>>(ug, part, NG_, 32);
    ln_k<<<B_, blk256, 0, stream>>>(part, 8, 1.f / NG_, ln_g, ln_b, cln);
    gatebias_k<<<dim3(B_, 3), blk256, 0, stream>>>(cln, Wf, bf, Ww, bw, Wo, bo, cf);
    gemm_bf16<<<gSml, blk256, 0, stream>>>(ug_bf, U0, U0, 1, Wpre + 1 * WS, cf + 0 * B_ * C_,
        F0, F0, F0, U0, U0, FW, FW, dgp, UW, NG_, 2);
    gemm_bf16<<<gSml, blk256, 0, stream>>>(ug_bf, U0, U0, 1, Wpre + 2 * WS, cf + 1 * B_ * C_,
        F0, F0, F0, U0, U0, FW, FW, wgp, UW, NG_, 2);
    gemm_bf16<<<gSml, blk256, 0, stream>>>(ug_bf, U0, U0, 1, Wpre + 3 * WS, cf + 2 * B_ * C_,
        dgp, wgp, ug, U0, U0, ag, bbg, og, UW, NG_, 4);          // a, bb, o
    scan_p1<<<B_ * 16, blk256, 0, stream>>>(ag, bbg, chA, chB, NG_, 16, 16, 0);
    scan_p2<<<B_, blk256, 0, stream>>>(chA, chB, chS, 16);
    scan_p3<<<B_ * 16, blk256, 0, stream>>>(ag, bbg, og, ug, chS, ygt, UW, NG_, 16, 16, 0);
    upsample_k<<<B_ * HW_, blk256, 0, stream>>>(ygt, bf5);       // ygs_bf

    // ---- fine: gates + bidirectional scans -------------------------------
    meanpart_k<<<dim3(B_, 32), blk256, 0, stream>>>(bu, part, HW_, 128);
    ln_k<<<B_, blk256, 0, stream>>>(part, 32, 1.f / HW_, ln_g, ln_b, cln);
    gatebias_k<<<dim3(B_, 3), blk256, 0, stream>>>(cln, Wf, bf, Ww, bw, Wo, bo, cf);
    gemm_bf16<<<gBig, blk256, 0, stream>>>(bf2, U0, U0, 1, Wpre + 1 * WS, cf + 0 * B_ * C_,
        F0, F0, F0, U0, U0, FW, FW, ba, UW, HW_, 2);             // dpre
    gemm_bf16<<<gBig, blk256, 0, stream>>>(bf2, U0, U0, 1, Wpre + 2 * WS, cf + 1 * B_ * C_,
        F0, F0, F0, U0, U0, FW, FW, bbb, UW, HW_, 2);            // wpre
    gemm_bf16<<<gBig, blk256, 0, stream>>>(bf2, U0, U0, 1, Wpre + 3 * WS, cf + 2 * B_ * C_,
        ba, bbb, bu, U0, U0, ba, bbb, bo_, UW, HW_, 4);          // a->ba, bb->bbb, o->bo_
    // forward scan -> bf1 (byf_bf); backward -> bf3 (byb_bf)
    scan_p1<<<B_ * 64, blk256, 0, stream>>>(ba, bbb, chA, chB, HW_, 64, 64, 0);
    scan_p2<<<B_, blk256, 0, stream>>>(chA, chB, chS, 64);
    scan_p3<<<B_ * 64, blk256, 0, stream>>>(ba, bbb, bo_, bu, chS, FW, bf1, HW_, 64, 64, 0);
    scan_p1<<<B_ * 64, blk256, 0, stream>>>(ba, bbb, chA, chB, HW_, 64, 64, 1);
    scan_p2<<<B_, blk256, 0, stream>>>(chA, chB, chS, 64);
    scan_p3<<<B_ * 64, blk256, 0, stream>>>(ba, bbb, bo_, bu, chS, FW, bf3, HW_, 64, 64, 1);

    // ---- rho combine (fused) ----------------------------------------------
    gemm_bf16<<<gBig, blk256, 0, stream>>>(bf2, bf1, bf3, 3, Wpre + 4 * WS, br,
        F0, F0, F0, bf1, bf3, FW, FW, ba, bf4, HW_, 5);          // y -> ba(fp32) + bf4

    // ---- lam / z (fused) ---------------------------------------------------
    gemm_bf16<<<gBig, blk256, 0, stream>>>(bf4, bf5, bf2, 3, Wpre + 7 * WS, bgi,
        ba, F0, F0, bf5, U0, FW, FW, FW, bf1, HW_, 6);           // z -> bf1

    // ---- local depthwise branch -------------------------------------------
    // bu (u fp32) is dead after the backward scan; reuse it for vmap fp32.
    dwconv_k<<<dim3(B_ * C_, 16), blk256, 0, stream>>>(x, dww, dwb, bu);    // vmap fp32
    transpose_bf_k<<<dim3(HW_ / 32, C_ / 32, B_), blkT, 0, stream>>>(bu, bf3); // vseq_bf
    gemm_bf16<<<gBig, blk256, 0, stream>>>(bf3, U0, U0, 1, Wpre + 10 * WS, bl,
        F0, F0, F0, U0, U0, FW, FW, FW, bf2, HW_, 7);            // v -> bf2
    gemm_bf16<<<gBig, blk256, 0, stream>>>(bf2, bf1, U0, 2, Wpre + 11 * WS, blf,
        F0, F0, F0, bf2, bf1, FW, FW, FW, bf3, HW_, 8);          // u_out -> bf3

    // ---- output projection + residual (fused transpose) -------------------
    gemm_bf16<<<gBig, blk256, 0, stream>>>(bf3, U0, U0, 1, Wpre + 13 * WS, bout,
        x, F0, F0, U0, U0, FW, FW, out, UW, HW_, 9);
}

// Round 6
// 764.875 us; speedup vs baseline: 1.5734x; 1.0891x over previous
//
#include <hip/hip_runtime.h>
#include <cstddef>

#define B_  8
#define C_  256
#define H_  64
#define W_  64
#define HW_ 4096
#define NG_ 256   // 16x16 global tokens

typedef unsigned short u16;
typedef __attribute__((ext_vector_type(8))) short short8;   // 8 bf16 = 4 VGPRs
typedef __attribute__((ext_vector_type(4))) float f32x4;

__device__ __forceinline__ float sigm(float v) { return 1.f / (1.f + expf(-v)); }

__device__ __forceinline__ u16 f2bf(float f) {
    union { float f; unsigned u; } x; x.f = f;
    unsigned r = x.u + 0x7fff + ((x.u >> 16) & 1);   // RNE
    return (u16)(r >> 16);
}
__device__ __forceinline__ float bf2f(u16 h) {
    union { unsigned u; float f; } x; x.u = ((unsigned)h) << 16;
    return x.f;
}

// ---------------------------------------------------------------------------
// Pre-transpose + bf16-convert the 14 weight seg-matrices:
// Wpre[s][n][k] = bf16(Wsrc[rowoff+k][n]).  grid (8, 8, 14), block (32,8)
// seg order: 0 Wt | 1 Wf | 2 Ww | 3 Wo | 4-6 Wr | 7-9 Wgi | 10 Wl | 11-12 Wlf | 13 Wout
// ---------------------------------------------------------------------------
__global__ __launch_bounds__(256) void prepw_k(
    const float* __restrict__ Wt, const float* __restrict__ Wf, const float* __restrict__ Ww,
    const float* __restrict__ Wo, const float* __restrict__ Wr, const float* __restrict__ Wgi,
    const float* __restrict__ Wl, const float* __restrict__ Wlf, const float* __restrict__ Wout,
    u16* __restrict__ Wpre)
{
    int s = blockIdx.z;
    const float* Wsrc; int rowoff = 0;
    switch (s) {
        case 0: Wsrc = Wt; break;
        case 1: Wsrc = Wf; break;
        case 2: Wsrc = Ww; break;
        case 3: Wsrc = Wo; break;
        case 4: case 5: case 6: Wsrc = Wr;  rowoff = (s - 4) * 256; break;
        case 7: case 8: case 9: Wsrc = Wgi; rowoff = (s - 7) * 256; break;
        case 10: Wsrc = Wl; break;
        case 11: case 12: Wsrc = Wlf; rowoff = (s - 11) * 256; break;
        default: Wsrc = Wout; break;
    }
    __shared__ float t[32][33];
    int k0 = blockIdx.y * 32, n0 = blockIdx.x * 32;
    int tx = threadIdx.x, ty = threadIdx.y;
#pragma unroll
    for (int i = 0; i < 32; i += 8)
        t[ty + i][tx] = Wsrc[(size_t)(rowoff + k0 + ty + i) * 256 + n0 + tx];
    __syncthreads();
    u16* op = Wpre + (size_t)s * 65536;
#pragma unroll
    for (int i = 0; i < 32; i += 8)
        op[(size_t)(n0 + ty + i) * 256 + k0 + tx] = f2bf(t[tx][ty + i]);
}

// ---------------------------------------------------------------------------
// bf16 MFMA GEMM with fused epilogues.
// Tile 64(m) x 128(n), 256 threads = 4 waves; wave = 32m x 64n via 2x4 mfma tiles.
// Modes:
//  1:  v = D+bias[n]+pos[(m%NTOK)*256+n]; out=v (fp32); out2=bf16(v)
//  10: v = D+bias[n]+pos[...]; out2=bf16(v) only
//  11: r=sigm(D+bias); y = r*bf(auxb0)+(1-r)*bf(auxb1); out2=bf16(y)
//  6:  l=sigm(D+bias); z = bf(auxb1)+l*bf(auxb0); out2=bf16(z)
//  7:  out2 = bf16(D+bias)
//  8:  e=sigm(D+bias); out2 = bf16(e*bf(auxb0)+(1-e)*bf(auxb1))
//  9:  out[(b*256+n)*4096+hw] = aux0[same] + D + bias[n]  (transposed + residual)
// ---------------------------------------------------------------------------
#define LDK 72   // padded LDS row stride (144 B): gcd(36,32)=4 -> 2-way = free
__global__ __launch_bounds__(256, 4) void gemm_bf16(
    const u16* __restrict__ A0, const u16* __restrict__ A1, const u16* __restrict__ A2,
    int nseg, const u16* __restrict__ Wpre, const float* __restrict__ bias,
    const float* __restrict__ pos, const float* __restrict__ aux0,
    const u16* __restrict__ auxb0, const u16* __restrict__ auxb1,
    float* __restrict__ out, u16* __restrict__ out2, int NTOK, int mode)
{
    __shared__ u16 Asm[64 * LDK];
    __shared__ u16 Bsm[128 * LDK];
    const int tid = threadIdx.x;
    const int lane = tid & 63, wave = tid >> 6;
    const int wm = wave & 1, wn = wave >> 1;
    const int m0 = blockIdx.x * 64, n0 = blockIdx.y * 128;
    const int l15 = lane & 15, lq = lane >> 4;

    f32x4 acc[2][4] = {};

    const int rowA = tid >> 2, kA = (tid & 3) * 16;   // 64 rows, 2 x short8 each
    const int rowB = tid >> 1, kB = (tid & 1) * 32;   // 128 rows, 4 x short8 each

    for (int seg = 0; seg < nseg; ++seg) {
        const u16* __restrict__ A = (seg == 0) ? A0 : ((seg == 1) ? A1 : A2);
        const u16* arow = A + (size_t)(m0 + rowA) * 256 + kA;
        const u16* wrow = Wpre + (size_t)seg * 65536 + (size_t)(n0 + rowB) * 256 + kB;

        for (int k0 = 0; k0 < 256; k0 += 64) {
            *(short8*)(&Asm[rowA * LDK + kA])     = *(const short8*)(arow + k0);
            *(short8*)(&Asm[rowA * LDK + kA + 8]) = *(const short8*)(arow + k0 + 8);
#pragma unroll
            for (int c = 0; c < 4; ++c)
                *(short8*)(&Bsm[rowB * LDK + kB + c * 8]) =
                    *(const short8*)(wrow + k0 + c * 8);
            __syncthreads();

#pragma unroll
            for (int ks = 0; ks < 2; ++ks) {
                short8 af[2], bfr[4];
#pragma unroll
                for (int i = 0; i < 2; ++i)
                    af[i] = *(const short8*)(&Asm[(wm * 32 + i * 16 + l15) * LDK + ks * 32 + lq * 8]);
#pragma unroll
                for (int j = 0; j < 4; ++j)
                    bfr[j] = *(const short8*)(&Bsm[(wn * 64 + j * 16 + l15) * LDK + ks * 32 + lq * 8]);
#pragma unroll
                for (int i = 0; i < 2; ++i)
#pragma unroll
                    for (int j = 0; j < 4; ++j)
                        acc[i][j] = __builtin_amdgcn_mfma_f32_16x16x32_bf16(
                            af[i], bfr[j], acc[i][j], 0, 0, 0);
            }
            __syncthreads();
        }
    }

    // epilogue: lane holds D[m = lq*4+r][n = l15] per 16x16 tile
#pragma unroll
    for (int i = 0; i < 2; ++i) {
        int mbase = m0 + wm * 32 + i * 16 + lq * 4;
#pragma unroll
        for (int j = 0; j < 4; ++j) {
            int n = n0 + wn * 64 + j * 16 + l15;
            if (mode == 9) {
                int b9 = mbase >> 12, hw = mbase & 4095;
                size_t oi = ((size_t)b9 * 256 + n) * 4096 + hw;
                float bn = bias[n];
                float4 xr = *(const float4*)(aux0 + oi);
                float4 res;
                res.x = xr.x + acc[i][j][0] + bn;
                res.y = xr.y + acc[i][j][1] + bn;
                res.z = xr.z + acc[i][j][2] + bn;
                res.w = xr.w + acc[i][j][3] + bn;
                *(float4*)(out + oi) = res;
                continue;
            }
            float bn = bias[n];
#pragma unroll
            for (int r = 0; r < 4; ++r) {
                int m = mbase + r;
                size_t idx = (size_t)m * 256 + n;
                float D = acc[i][j][r] + bn;
                if (mode == 1) {
                    float v = D + pos[(size_t)(m % NTOK) * 256 + n];
                    out[idx] = v; out2[idx] = f2bf(v);
                } else if (mode == 10) {
                    float v = D + pos[(size_t)(m % NTOK) * 256 + n];
                    out2[idx] = f2bf(v);
                } else if (mode == 11) {
                    float r_ = sigm(D);
                    out2[idx] = f2bf(r_ * bf2f(auxb0[idx]) + (1.f - r_) * bf2f(auxb1[idx]));
                } else if (mode == 6) {
                    float l = sigm(D);
                    out2[idx] = f2bf(bf2f(auxb1[idx]) + l * bf2f(auxb0[idx]));
                } else if (mode == 7) {
                    out2[idx] = f2bf(D);
                } else { // 8
                    float e = sigm(D);
                    out2[idx] = f2bf(e * bf2f(auxb0[idx]) + (1.f - e) * bf2f(auxb1[idx]));
                }
            }
        }
    }
}

// ---------------------------------------------------------------------------
// Fused triple-gate GEMM: computes dpre/wpre/opre with three weight matrices
// (Wg = Wf|Ww|Wo pre-transposed, contiguous segs), then emits
// a = sigm(-dpre), bb = (1-a)*sigm(wpre)*u, o_bf = bf16(sigm(opre)).
// cf: per-batch bias rows [gate][batch][n].
// ---------------------------------------------------------------------------
__global__ __launch_bounds__(256, 3) void gemm_gates3(
    const u16* __restrict__ A0, const u16* __restrict__ Wg, const float* __restrict__ cf,
    const u16* __restrict__ ubf, float* __restrict__ aF, float* __restrict__ bbF,
    u16* __restrict__ obf, int NTOK)
{
    __shared__ u16 Asm[64 * LDK];
    __shared__ u16 Bsm[128 * LDK];
    const int tid = threadIdx.x;
    const int lane = tid & 63, wave = tid >> 6;
    const int wm = wave & 1, wn = wave >> 1;
    const int m0 = blockIdx.x * 64, n0 = blockIdx.y * 128;
    const int l15 = lane & 15, lq = lane >> 4;

    f32x4 acc[3][2][4] = {};

    const int rowA = tid >> 2, kA = (tid & 3) * 16;
    const int rowB = tid >> 1, kB = (tid & 1) * 32;
    const u16* arow = A0 + (size_t)(m0 + rowA) * 256 + kA;

    for (int k0 = 0; k0 < 256; k0 += 64) {
        *(short8*)(&Asm[rowA * LDK + kA])     = *(const short8*)(arow + k0);
        *(short8*)(&Asm[rowA * LDK + kA + 8]) = *(const short8*)(arow + k0 + 8);
#pragma unroll
        for (int ws = 0; ws < 3; ++ws) {
            const u16* wrow = Wg + (size_t)ws * 65536 + (size_t)(n0 + rowB) * 256 + kB;
#pragma unroll
            for (int c = 0; c < 4; ++c)
                *(short8*)(&Bsm[rowB * LDK + kB + c * 8]) =
                    *(const short8*)(wrow + k0 + c * 8);
            __syncthreads();
#pragma unroll
            for (int ks = 0; ks < 2; ++ks) {
                short8 af[2], bfr[4];
#pragma unroll
                for (int i = 0; i < 2; ++i)
                    af[i] = *(const short8*)(&Asm[(wm * 32 + i * 16 + l15) * LDK + ks * 32 + lq * 8]);
#pragma unroll
                for (int j = 0; j < 4; ++j)
                    bfr[j] = *(const short8*)(&Bsm[(wn * 64 + j * 16 + l15) * LDK + ks * 32 + lq * 8]);
#pragma unroll
                for (int i = 0; i < 2; ++i)
#pragma unroll
                    for (int j = 0; j < 4; ++j)
                        acc[ws][i][j] = __builtin_amdgcn_mfma_f32_16x16x32_bf16(
                            af[i], bfr[j], acc[ws][i][j], 0, 0, 0);
            }
            __syncthreads();
        }
    }

#pragma unroll
    for (int i = 0; i < 2; ++i) {
        int mbase = m0 + wm * 32 + i * 16 + lq * 4;
        int bt_ = mbase / NTOK;
#pragma unroll
        for (int j = 0; j < 4; ++j) {
            int n = n0 + wn * 64 + j * 16 + l15;
            float cD = cf[((size_t)0 * B_ + bt_) * C_ + n];
            float cW = cf[((size_t)1 * B_ + bt_) * C_ + n];
            float cO = cf[((size_t)2 * B_ + bt_) * C_ + n];
#pragma unroll
            for (int r = 0; r < 4; ++r) {
                size_t idx = (size_t)(mbase + r) * 256 + n;
                float a_ = sigm(-(acc[0][i][j][r] + cD));
                float g_ = sigm(acc[1][i][j][r] + cW);
                float o_ = sigm(acc[2][i][j][r] + cO);
                float u_ = bf2f(ubf[idx]);
                aF[idx]  = a_;
                bbF[idx] = (1.f - a_) * g_ * u_;
                obf[idx] = f2bf(o_);
            }
        }
    }
}

// ---------------------------------------------------------------------------
// Transpose x [B][C][HW] fp32 -> seq_bf [B][HW][C] bf16.
// grid (HW_/32, C_/32, B), block (32,8)
// ---------------------------------------------------------------------------
__global__ __launch_bounds__(256) void transpose_bf_k(const float* __restrict__ in,
                                                      u16* __restrict__ outb)
{
    __shared__ float t[32][33];
    int b = blockIdx.z;
    int r0 = blockIdx.y * 32, c0 = blockIdx.x * 32;   // r = channel, c = hw
    int tx = threadIdx.x, ty = threadIdx.y;
    const float* ip = in + (size_t)b * HW_ * C_;
    u16* op = outb + (size_t)b * HW_ * C_;
#pragma unroll
    for (int k = 0; k < 32; k += 8)
        t[ty + k][tx] = ip[(size_t)(r0 + ty + k) * HW_ + c0 + tx];
    __syncthreads();
#pragma unroll
    for (int k = 0; k < 32; k += 8)
        op[(size_t)(c0 + ty + k) * C_ + r0 + tx] = f2bf(t[tx][ty + k]);
}

// Fused depthwise 3x3 conv + transpose: x[B][C][HW] -> vseq_bf[B][HW][C] bf16.
// Same tiling as transpose_bf_k; conv reads coalesced along w.
__global__ __launch_bounds__(256) void dwconvt2_k(const float* __restrict__ x,
                                                  const float* __restrict__ dww,
                                                  const float* __restrict__ dwb,
                                                  u16* __restrict__ vseq)
{
    __shared__ float t[32][33];
    int b = blockIdx.z;
    int r0 = blockIdx.y * 32, c0 = blockIdx.x * 32;   // r = channel, c = hw
    int tx = threadIdx.x, ty = threadIdx.y;
#pragma unroll
    for (int k = 0; k < 32; k += 8) {
        int ch = r0 + ty + k;
        int hw = c0 + tx;
        int h = hw >> 6, w = hw & 63;
        const float* xp = x + ((size_t)b * C_ + ch) * HW_;
        const float* wp = dww + ch * 9;
        float acc = dwb[ch];
#pragma unroll
        for (int dy = 0; dy < 3; ++dy) {
            int hh = h + dy - 1;
            if (hh < 0 || hh > 63) continue;
#pragma unroll
            for (int dx = 0; dx < 3; ++dx) {
                int ww = w + dx - 1;
                if (ww < 0 || ww > 63) continue;
                acc += xp[hh * 64 + ww] * wp[dy * 3 + dx];
            }
        }
        t[ty + k][tx] = acc;
    }
    __syncthreads();
    u16* op = vseq + (size_t)b * HW_ * C_;
#pragma unroll
    for (int k = 0; k < 32; k += 8)
        op[(size_t)(c0 + ty + k) * C_ + r0 + tx] = f2bf(t[tx][ty + k]);
}

// 4x4 avg pool x -> seqg_bf[B][256][C] bf16.  grid (B, C), block 256 = ghw
__global__ __launch_bounds__(256) void pool_k(const float* __restrict__ x, u16* __restrict__ seqg)
{
    int b = blockIdx.x, c = blockIdx.y, ghw = threadIdx.x;
    int gh = ghw >> 4, gw = ghw & 15;
    const float* xp = x + ((size_t)b * C_ + c) * HW_;
    float s = 0.f;
#pragma unroll
    for (int dy = 0; dy < 4; ++dy)
#pragma unroll
        for (int dx = 0; dx < 4; ++dx)
            s += xp[(gh * 4 + dy) * W_ + gw * 4 + dx];
    seqg[((size_t)b * NG_ + ghw) * C_ + c] = f2bf(s * (1.f / 16.f));
}

// pos_fine [1][256][32][32] -> posF[4096][256] fp32, half-pixel bilinear 2x
__global__ __launch_bounds__(256) void posfine_k(const float* __restrict__ pf, float* __restrict__ posF)
{
    int hw = blockIdx.x, c = threadIdx.x;
    int h = hw >> 6, w = hw & 63;
    float fy = h * 0.5f - 0.25f, fx = w * 0.5f - 0.25f;
    int y0 = (int)floorf(fy); float wy = fy - (float)y0;
    int x0 = (int)floorf(fx); float wx = fx - (float)x0;
    int y0c = min(max(y0, 0), 31), y1c = min(max(y0 + 1, 0), 31);
    int x0c = min(max(x0, 0), 31), x1c = min(max(x0 + 1, 0), 31);
    const float* p = pf + (size_t)c * 1024;
    float v = (1.f - wy) * ((1.f - wx) * p[y0c * 32 + x0c] + wx * p[y0c * 32 + x1c])
            +        wy  * ((1.f - wx) * p[y1c * 32 + x0c] + wx * p[y1c * 32 + x1c]);
    posF[(size_t)hw * C_ + c] = v;
}

// pos_glob -> posG[256][256] fp32: antialiased 2x downsample (4-tap triangle)
__global__ __launch_bounds__(256) void posglob_k(const float* __restrict__ pg, float* __restrict__ posG)
{
    int ghw = blockIdx.x, c = threadIdx.x;
    int gh = ghw >> 4, gw = ghw & 15;
    const float wt[4] = {0.125f, 0.375f, 0.375f, 0.125f};
    float wy[4], wx[4]; int jy[4], jx[4];
    float sy = 0.f, sx = 0.f;
#pragma unroll
    for (int k = 0; k < 4; ++k) {
        jy[k] = 2 * gh - 1 + k; jx[k] = 2 * gw - 1 + k;
        wy[k] = (jy[k] >= 0 && jy[k] < 32) ? wt[k] : 0.f; sy += wy[k];
        wx[k] = (jx[k] >= 0 && jx[k] < 32) ? wt[k] : 0.f; sx += wx[k];
    }
    const float* p = pg + (size_t)c * 1024;
    float acc = 0.f;
#pragma unroll
    for (int ky = 0; ky < 4; ++ky) {
        if (wy[ky] == 0.f) continue;
        float row = 0.f;
#pragma unroll
        for (int kx = 0; kx < 4; ++kx)
            if (wx[kx] != 0.f) row += wx[kx] * p[jy[ky] * 32 + jx[kx]];
        acc += wy[ky] * row;
    }
    posG[(size_t)ghw * C_ + c] = acc / (sy * sx);
}

// y_g[B][256][C] fp32 -> ygs_bf[B][4096][C] bf16: half-pixel bilinear 4x up
__global__ __launch_bounds__(256) void upsample_k(const float* __restrict__ yg, u16* __restrict__ ygs)
{
    int b = blockIdx.x >> 12, hw = blockIdx.x & 4095, c = threadIdx.x;
    int h = hw >> 6, w = hw & 63;
    float fy = h * 0.25f - 0.375f, fx = w * 0.25f - 0.375f;
    int y0 = (int)floorf(fy); float wy = fy - (float)y0;
    int x0 = (int)floorf(fx); float wx = fx - (float)x0;
    int y0c = min(max(y0, 0), 15), y1c = min(max(y0 + 1, 0), 15);
    int x0c = min(max(x0, 0), 15), x1c = min(max(x0 + 1, 0), 15);
    const float* p = yg + (size_t)b * NG_ * C_ + c;
    float v = (1.f - wy) * ((1.f - wx) * p[(y0c * 16 + x0c) * C_] + wx * p[(y0c * 16 + x1c) * C_])
            +        wy  * ((1.f - wx) * p[(y1c * 16 + x0c) * C_] + wx * p[(y1c * 16 + x1c) * C_]);
    ygs[((size_t)b * HW_ + hw) * C_ + c] = f2bf(v);
}

// partial token-mean fp32: grid (B, S), block 256=c
__global__ __launch_bounds__(256) void meanpart_k(const float* __restrict__ u, float* __restrict__ part,
                                                  int Ntok, int chunkLen)
{
    int b = blockIdx.x, s = blockIdx.y, c = threadIdx.x;
    float acc = 0.f;
    for (int i = 0; i < chunkLen; ++i) {
        int t = s * chunkLen + i;
        acc += u[((size_t)b * Ntok + t) * C_ + c];
    }
    part[((size_t)b * gridDim.y + s) * C_ + c] = acc;
}

// partial token-mean bf16 input: grid (B, S), block 256=c
__global__ __launch_bounds__(256) void meanpart_bf_k(const u16* __restrict__ u, float* __restrict__ part,
                                                     int Ntok, int chunkLen)
{
    int b = blockIdx.x, s = blockIdx.y, c = threadIdx.x;
    float acc = 0.f;
    for (int i = 0; i < chunkLen; ++i) {
        int t = s * chunkLen + i;
        acc += bf2f(u[((size_t)b * Ntok + t) * C_ + c]);
    }
    part[((size_t)b * gridDim.y + s) * C_ + c] = acc;
}

// finish mean + LayerNorm over C.  grid (B), block 256
__global__ __launch_bounds__(256) void ln_k(const float* __restrict__ part, int S, float invN,
                                            const float* __restrict__ g, const float* __restrict__ bta,
                                            float* __restrict__ cout)
{
    __shared__ float red[256];
    int c = threadIdx.x, b = blockIdx.x;
    float v = 0.f;
    for (int s = 0; s < S; ++s) v += part[((size_t)b * S + s) * C_ + c];
    v *= invN;
    red[c] = v; __syncthreads();
    for (int st = 128; st > 0; st >>= 1) { if (c < st) red[c] += red[c + st]; __syncthreads(); }
    float m = red[0] * (1.f / 256.f);
    __syncthreads();
    float d = v - m;
    red[c] = d * d; __syncthreads();
    for (int st = 128; st > 0; st >>= 1) { if (c < st) red[c] += red[c + st]; __syncthreads(); }
    float var = red[0] * (1.f / 256.f);
    cout[(size_t)b * C_ + c] = d * rsqrtf(var + 1e-5f) * g[c] + bta[c];
}

// per-batch gate bias rows: cf[gate][b][n] = c[b] @ Wg[256:,:] + bg.  grid (B, 3), block 256
__global__ __launch_bounds__(256) void gatebias_k(const float* __restrict__ cvec,
    const float* __restrict__ Wf, const float* __restrict__ bf,
    const float* __restrict__ Ww, const float* __restrict__ bw,
    const float* __restrict__ Wo, const float* __restrict__ bo,
    float* __restrict__ outb)
{
    int n = threadIdx.x, b = blockIdx.x, gate = blockIdx.y;
    const float* Wm = (gate == 0) ? Wf : ((gate == 1) ? Ww : Wo);
    const float* bi = (gate == 0) ? bf : ((gate == 1) ? bw : bo);
    __shared__ float cs[256];
    cs[n] = cvec[(size_t)b * C_ + n];
    __syncthreads();
    float acc = bi[n];
    for (int k = 0; k < 256; ++k)
        acc += cs[k] * Wm[(size_t)(256 + k) * C_ + n];
    outb[((size_t)gate * B_ + b) * C_ + n] = acc;
}

// ---------------- merged bidirectional chunked scan ----------------------
// p1b: per-chunk (A,B) for fwd and (optionally) bwd over the SAME token range.
// bwd chunk index for token range [ch*CL,(ch+1)*CL) is nchunk-1-ch.
__global__ __launch_bounds__(256) void scan_p1b(
    const float* __restrict__ a, const float* __restrict__ bb,
    float* __restrict__ AbF, float* __restrict__ BbF,
    float* __restrict__ AbB, float* __restrict__ BbB,
    int Ntok, int nchunk, int both)
{
    int c = threadIdx.x;
    int ch = blockIdx.x % nchunk;
    int b = blockIdx.x / nchunk;
    int CL = Ntok / nchunk;
    size_t base = ((size_t)b * Ntok + (size_t)ch * CL) * C_ + c;
    float sA = 1.f, sB = 0.f;
    for (int i = 0; i < CL; ++i) {
        float av = a[base + (size_t)i * C_];
        sB = av * sB + bb[base + (size_t)i * C_];
        sA *= av;
    }
    size_t o = ((size_t)b * nchunk + ch) * C_ + c;
    AbF[o] = sA; BbF[o] = sB;
    if (both) {
        sA = 1.f; sB = 0.f;
        for (int i = CL - 1; i >= 0; --i) {
            float av = a[base + (size_t)i * C_];
            sB = av * sB + bb[base + (size_t)i * C_];
            sA *= av;
        }
        size_t ob = ((size_t)b * nchunk + (nchunk - 1 - ch)) * C_ + c;
        AbB[ob] = sA; BbB[ob] = sB;
    }
}

__global__ __launch_bounds__(256) void scan_p2b(
    const float* __restrict__ AbF, const float* __restrict__ BbF, float* __restrict__ SbF,
    const float* __restrict__ AbB, const float* __restrict__ BbB, float* __restrict__ SbB,
    int nchunk, int both)
{
    int c = threadIdx.x, b = blockIdx.x;
    float s = 0.f;
    for (int ch = 0; ch < nchunk; ++ch) {
        size_t o = ((size_t)b * nchunk + ch) * C_ + c;
        SbF[o] = s;
        s = AbF[o] * s + BbF[o];
    }
    if (both) {
        s = 0.f;
        for (int ch = 0; ch < nchunk; ++ch) {
            size_t o = ((size_t)b * nchunk + ch) * C_ + c;
            SbB[o] = s;
            s = AbB[o] * s + BbB[o];
        }
    }
}

// p3b: replay fwd (and bwd) over the chunk's token range; o,u read as bf16.
// Outputs: yout fp32 (may be null), ybfF bf16 (may be null), ybfB bf16 (if both).
__global__ __launch_bounds__(256) void scan_p3b(
    const float* __restrict__ a, const float* __restrict__ bb,
    const u16* __restrict__ obf, const u16* __restrict__ ubf,
    const float* __restrict__ SbF, const float* __restrict__ SbB,
    float* __restrict__ yout, u16* __restrict__ ybfF, u16* __restrict__ ybfB,
    int Ntok, int nchunk, int both)
{
    int c = threadIdx.x;
    int ch = blockIdx.x % nchunk;
    int b = blockIdx.x / nchunk;
    int CL = Ntok / nchunk;
    size_t base = ((size_t)b * Ntok + (size_t)ch * CL) * C_ + c;
    float s = SbF[((size_t)b * nchunk + ch) * C_ + c];
    for (int i = 0; i < CL; ++i) {
        size_t idx = base + (size_t)i * C_;
        float av = a[idx];
        s = av * s + bb[idx];
        float ov = bf2f(obf[idx]);
        float y = ov * s + (1.f - ov) * bf2f(ubf[idx]);
        if (yout) yout[idx] = y;
        if (ybfF) ybfF[idx] = f2bf(y);
    }
    if (both) {
        float sb = SbB[((size_t)b * nchunk + (nchunk - 1 - ch)) * C_ + c];
        for (int i = CL - 1; i >= 0; --i) {
            size_t idx = base + (size_t)i * C_;
            float av = a[idx];
            sb = av * sb + bb[idx];
            float ov = bf2f(obf[idx]);
            ybfB[idx] = f2bf(ov * sb + (1.f - ov) * bf2f(ubf[idx]));
        }
    }
}

// ===========================================================================
extern "C" void kernel_launch(void* const* d_in, const int* in_sizes, int n_in,
                              void* d_out, int out_size, void* d_ws, size_t ws_size,
                              hipStream_t stream)
{
    const float* x        = (const float*)d_in[0];
    const float* Wt       = (const float*)d_in[1];
    const float* bt       = (const float*)d_in[2];
    const float* pos_fine = (const float*)d_in[3];
    const float* pos_glob = (const float*)d_in[4];
    const float* ln_g     = (const float*)d_in[5];
    const float* ln_b     = (const float*)d_in[6];
    const float* Wf       = (const float*)d_in[7];
    const float* bf       = (const float*)d_in[8];
    const float* Ww       = (const float*)d_in[9];
    const float* bw       = (const float*)d_in[10];
    const float* Wo       = (const float*)d_in[11];
    const float* bo       = (const float*)d_in[12];
    const float* Wr       = (const float*)d_in[13];
    const float* br       = (const float*)d_in[14];
    const float* Wgi      = (const float*)d_in[15];
    const float* bgi      = (const float*)d_in[16];
    const float* dww      = (const float*)d_in[17];
    const float* dwb      = (const float*)d_in[18];
    const float* Wl       = (const float*)d_in[19];
    const float* bl       = (const float*)d_in[20];
    const float* Wlf      = (const float*)d_in[21];
    const float* blf      = (const float*)d_in[22];
    const float* Wout     = (const float*)d_in[23];
    const float* bout     = (const float*)d_in[24];
    float* out = (float*)d_out;

    float* w = (float*)d_ws;
    const size_t BNC = (size_t)B_ * HW_ * C_;        // 8,388,608 elements
    // fp32 big buffers
    float* bu  = w + 0 * BNC;   // free region -> bwd chunk scratch
    float* ba  = w + 1 * BNC;   // a (fine)
    float* bbb = w + 2 * BNC;   // bb (fine)
    float* bo_ = w + 3 * BNC;   // o_bf lives here as u16
    // bf16 big buffers
    u16* bf1 = (u16*)(w + 4 * BNC);                  // seq_bf -> yf_bf -> z_bf
    u16* bf2 = bf1 + BNC;                            // u_bf -> v_bf
    u16* bf3 = bf2 + BNC;                            // yb_bf -> vseq_bf -> uo_bf
    u16* bf4 = bf3 + BNC;                            // y_bf
    u16* bf5 = bf4 + BNC;                            // ygs_bf (long-lived)
    float* ext = w + 4 * BNC + 5 * (BNC / 2);
    float* posF = ext;  ext += (size_t)HW_ * C_;
    float* posG = ext;  ext += (size_t)NG_ * C_;
    float* part = ext;  ext += (size_t)B_ * 32 * C_;
    float* cln  = ext;  ext += (size_t)B_ * C_;
    float* cf   = ext;  ext += (size_t)3 * B_ * C_;
    float* ug   = ext;  ext += (size_t)B_ * NG_ * C_;
    float* ag   = ext;  ext += (size_t)B_ * NG_ * C_;
    float* bbg  = ext;  ext += (size_t)B_ * NG_ * C_;
    float* ygt  = ext;  ext += (size_t)B_ * NG_ * C_;
    float* chAF = ext;  ext += (size_t)B_ * 64 * C_;
    float* chBF = ext;  ext += (size_t)B_ * 64 * C_;
    float* chSF = ext;  ext += (size_t)B_ * 64 * C_;
    u16* seqg_bf = (u16*)ext;  ext += (size_t)B_ * NG_ * C_ / 2;
    u16* ug_bf   = (u16*)ext;  ext += (size_t)B_ * NG_ * C_ / 2;
    u16* og_bf   = (u16*)ext;  ext += (size_t)B_ * NG_ * C_ / 2;
    u16* Wpre    = (u16*)ext;  // 14 * 65536 bf16 = 1.75 MiB
    // carve bwd scratch + fine o_bf from free fp32 regions
    float* chAB = bu;                       // B*64*C
    float* chBB = bu + (size_t)B_ * 64 * C_;
    float* chSB = bu + (size_t)2 * B_ * 64 * C_;
    u16* obf    = (u16*)bo_;                // fine o gate, bf16

    const dim3 blk256(256);
    const dim3 blkT(32, 8);
    const dim3 gBig(B_ * HW_ / 64, 2);    // 512 x 2 = 1024 blocks
    const dim3 gSml(B_ * NG_ / 64, 2);    // 32 x 2 blocks
    const size_t WS = 65536;              // bf16 elems per weight seg
    const float *F0 = nullptr; const u16 *U0 = nullptr;
    float *FW = nullptr; u16 *UW = nullptr;

    // ---- weight prep ------------------------------------------------------
    prepw_k<<<dim3(8, 8, 14), blkT, 0, stream>>>(Wt, Wf, Ww, Wo, Wr, Wgi, Wl, Wlf, Wout, Wpre);

    // ---- fine: seq + u ----------------------------------------------------
    transpose_bf_k<<<dim3(HW_ / 32, C_ / 32, B_), blkT, 0, stream>>>(x, bf1);  // seq_bf
    posfine_k<<<HW_, blk256, 0, stream>>>(pos_fine, posF);
    gemm_bf16<<<gBig, blk256, 0, stream>>>(bf1, U0, U0, 1, Wpre + 0 * WS, bt,
        posF, F0, U0, U0, FW, bf2, HW_, 10);                     // u_bf only

    // ---- global branch ----------------------------------------------------
    pool_k<<<dim3(B_, C_), blk256, 0, stream>>>(x, seqg_bf);
    posglob_k<<<NG_, blk256, 0, stream>>>(pos_glob, posG);
    gemm_bf16<<<gSml, blk256, 0, stream>>>(seqg_bf, U0, U0, 1, Wpre + 0 * WS, bt,
        posG, F0, U0, U0, ug, ug_bf, NG_, 1);                    // u_g fp32 + bf16
    meanpart_k<<<dim3(B_, 8), blk256, 0, stream>>>(ug, part, NG_, 32);
    ln_k<<<B_, blk256, 0, stream>>>(part, 8, 1.f / NG_, ln_g, ln_b, cln);
    gatebias_k<<<dim3(B_, 3), blk256, 0, stream>>>(cln, Wf, bf, Ww, bw, Wo, bo, cf);
    gemm_gates3<<<gSml, blk256, 0, stream>>>(ug_bf, Wpre + 1 * WS, cf, ug_bf,
        ag, bbg, og_bf, NG_);
    scan_p1b<<<B_ * 16, blk256, 0, stream>>>(ag, bbg, chAF, chBF, FW, FW, NG_, 16, 0);
    scan_p2b<<<B_, blk256, 0, stream>>>(chAF, chBF, chSF, F0, F0, FW, 16, 0);
    scan_p3b<<<B_ * 16, blk256, 0, stream>>>(ag, bbg, og_bf, ug_bf, chSF, F0,
        ygt, UW, UW, NG_, 16, 0);
    upsample_k<<<B_ * HW_, blk256, 0, stream>>>(ygt, bf5);       // ygs_bf

    // ---- fine: gates + merged bidirectional scan --------------------------
    meanpart_bf_k<<<dim3(B_, 32), blk256, 0, stream>>>(bf2, part, HW_, 128);
    ln_k<<<B_, blk256, 0, stream>>>(part, 32, 1.f / HW_, ln_g, ln_b, cln);
    gatebias_k<<<dim3(B_, 3), blk256, 0, stream>>>(cln, Wf, bf, Ww, bw, Wo, bo, cf);
    gemm_gates3<<<gBig, blk256, 0, stream>>>(bf2, Wpre + 1 * WS, cf, bf2,
        ba, bbb, obf, HW_);
    scan_p1b<<<B_ * 64, blk256, 0, stream>>>(ba, bbb, chAF, chBF, chAB, chBB, HW_, 64, 1);
    scan_p2b<<<B_, blk256, 0, stream>>>(chAF, chBF, chSF, chAB, chBB, chSB, 64, 1);
    scan_p3b<<<B_ * 64, blk256, 0, stream>>>(ba, bbb, obf, bf2, chSF, chSB,
        FW, bf1, bf3, HW_, 64, 1);                               // yf->bf1, yb->bf3

    // ---- rho combine (fused) ----------------------------------------------
    gemm_bf16<<<gBig, blk256, 0, stream>>>(bf2, bf1, bf3, 3, Wpre + 4 * WS, br,
        F0, F0, bf1, bf3, FW, bf4, HW_, 11);                     // y_bf -> bf4

    // ---- lam / z (fused) ---------------------------------------------------
    gemm_bf16<<<gBig, blk256, 0, stream>>>(bf4, bf5, bf2, 3, Wpre + 7 * WS, bgi,
        F0, F0, bf5, bf4, FW, bf1, HW_, 6);                      // z_bf -> bf1

    // ---- local depthwise branch (fused conv+transpose) --------------------
    dwconvt2_k<<<dim3(HW_ / 32, C_ / 32, B_), blkT, 0, stream>>>(x, dww, dwb, bf3); // vseq_bf
    gemm_bf16<<<gBig, blk256, 0, stream>>>(bf3, U0, U0, 1, Wpre + 10 * WS, bl,
        F0, F0, U0, U0, FW, bf2, HW_, 7);                        // v_bf -> bf2
    gemm_bf16<<<gBig, blk256, 0, stream>>>(bf2, bf1, U0, 2, Wpre + 11 * WS, blf,
        F0, F0, bf2, bf1, FW, bf3, HW_, 8);                      // uo_bf -> bf3

    // ---- output projection + residual (fused transpose) -------------------
    gemm_bf16<<<gBig, blk256, 0, stream>>>(bf3, U0, U0, 1, Wpre + 13 * WS, bout,
        F0, x, U0, U0, out, UW, HW_, 9);
}

// Round 7
// 662.151 us; speedup vs baseline: 1.8175x; 1.1551x over previous
//
#include <hip/hip_runtime.h>
#include <cstddef>

#define B_  8
#define C_  256
#define H_  64
#define W_  64
#define HW_ 4096
#define NG_ 256   // 16x16 global tokens

typedef unsigned short u16;
typedef __attribute__((ext_vector_type(8))) short short8;   // 8 bf16 = 4 VGPRs
typedef __attribute__((ext_vector_type(4))) float f32x4;

__device__ __forceinline__ float sigm(float v) { return 1.f / (1.f + expf(-v)); }

__device__ __forceinline__ u16 f2bf(float f) {
    union { float f; unsigned u; } x; x.f = f;
    unsigned r = x.u + 0x7fff + ((x.u >> 16) & 1);   // RNE
    return (u16)(r >> 16);
}
__device__ __forceinline__ float bf2f(u16 h) {
    union { unsigned u; float f; } x; x.u = ((unsigned)h) << 16;
    return x.f;
}

// ---------------------------------------------------------------------------
// Pre-transpose + bf16-convert the 14 weight seg-matrices:
// Wpre[s][n][k] = bf16(Wsrc[rowoff+k][n]).  grid (8, 8, 14), block (32,8)
// seg order: 0 Wt | 1 Wf | 2 Ww | 3 Wo | 4-6 Wr | 7-9 Wgi | 10 Wl | 11-12 Wlf | 13 Wout
// ---------------------------------------------------------------------------
__global__ __launch_bounds__(256) void prepw_k(
    const float* __restrict__ Wt, const float* __restrict__ Wf, const float* __restrict__ Ww,
    const float* __restrict__ Wo, const float* __restrict__ Wr, const float* __restrict__ Wgi,
    const float* __restrict__ Wl, const float* __restrict__ Wlf, const float* __restrict__ Wout,
    u16* __restrict__ Wpre)
{
    int s = blockIdx.z;
    const float* Wsrc; int rowoff = 0;
    switch (s) {
        case 0: Wsrc = Wt; break;
        case 1: Wsrc = Wf; break;
        case 2: Wsrc = Ww; break;
        case 3: Wsrc = Wo; break;
        case 4: case 5: case 6: Wsrc = Wr;  rowoff = (s - 4) * 256; break;
        case 7: case 8: case 9: Wsrc = Wgi; rowoff = (s - 7) * 256; break;
        case 10: Wsrc = Wl; break;
        case 11: case 12: Wsrc = Wlf; rowoff = (s - 11) * 256; break;
        default: Wsrc = Wout; break;
    }
    __shared__ float t[32][33];
    int k0 = blockIdx.y * 32, n0 = blockIdx.x * 32;
    int tx = threadIdx.x, ty = threadIdx.y;
#pragma unroll
    for (int i = 0; i < 32; i += 8)
        t[ty + i][tx] = Wsrc[(size_t)(rowoff + k0 + ty + i) * 256 + n0 + tx];
    __syncthreads();
    u16* op = Wpre + (size_t)s * 65536;
#pragma unroll
    for (int i = 0; i < 32; i += 8)
        op[(size_t)(n0 + ty + i) * 256 + k0 + tx] = f2bf(t[tx][ty + i]);
}

// ---------------------------------------------------------------------------
// bf16 MFMA GEMM with fused epilogues.
// Tile 64(m) x 128(n), 256 threads = 4 waves; wave = 32m x 64n via 2x4 mfma tiles.
// Modes:
//  1:  v = D+bias[n]+pos[(m%NTOK)*256+n]; out=v (fp32); out2=bf16(v)
//  10: v = D+bias[n]+pos[...]; out2=bf16(v) only
//  11: r=sigm(D+bias); y = r*bf(auxb0)+(1-r)*bf(auxb1); out2=bf16(y)
//  6:  l=sigm(D+bias); z = bf(auxb1)+l*bf(auxb0); out2=bf16(z)
//  7:  out2 = bf16(D+bias)
//  8:  e=sigm(D+bias); out2 = bf16(e*bf(auxb0)+(1-e)*bf(auxb1))
//  9:  out[(b*256+n)*4096+hw] = aux0[same] + D + bias[n]  (transposed + residual)
// ---------------------------------------------------------------------------
#define LDK 72   // padded LDS row stride (144 B): gcd(36,32)=4 -> 2-way = free
__global__ __launch_bounds__(256, 4) void gemm_bf16(
    const u16* __restrict__ A0, const u16* __restrict__ A1, const u16* __restrict__ A2,
    int nseg, const u16* __restrict__ Wpre, const float* __restrict__ bias,
    const float* __restrict__ pos, const float* __restrict__ aux0,
    const u16* __restrict__ auxb0, const u16* __restrict__ auxb1,
    float* __restrict__ out, u16* __restrict__ out2, int NTOK, int mode)
{
    __shared__ u16 Asm[64 * LDK];
    __shared__ u16 Bsm[128 * LDK];
    const int tid = threadIdx.x;
    const int lane = tid & 63, wave = tid >> 6;
    const int wm = wave & 1, wn = wave >> 1;
    const int m0 = blockIdx.x * 64, n0 = blockIdx.y * 128;
    const int l15 = lane & 15, lq = lane >> 4;

    f32x4 acc[2][4] = {};

    const int rowA = tid >> 2, kA = (tid & 3) * 16;   // 64 rows, 2 x short8 each
    const int rowB = tid >> 1, kB = (tid & 1) * 32;   // 128 rows, 4 x short8 each

    for (int seg = 0; seg < nseg; ++seg) {
        const u16* __restrict__ A = (seg == 0) ? A0 : ((seg == 1) ? A1 : A2);
        const u16* arow = A + (size_t)(m0 + rowA) * 256 + kA;
        const u16* wrow = Wpre + (size_t)seg * 65536 + (size_t)(n0 + rowB) * 256 + kB;

        for (int k0 = 0; k0 < 256; k0 += 64) {
            *(short8*)(&Asm[rowA * LDK + kA])     = *(const short8*)(arow + k0);
            *(short8*)(&Asm[rowA * LDK + kA + 8]) = *(const short8*)(arow + k0 + 8);
#pragma unroll
            for (int c = 0; c < 4; ++c)
                *(short8*)(&Bsm[rowB * LDK + kB + c * 8]) =
                    *(const short8*)(wrow + k0 + c * 8);
            __syncthreads();

#pragma unroll
            for (int ks = 0; ks < 2; ++ks) {
                short8 af[2], bfr[4];
#pragma unroll
                for (int i = 0; i < 2; ++i)
                    af[i] = *(const short8*)(&Asm[(wm * 32 + i * 16 + l15) * LDK + ks * 32 + lq * 8]);
#pragma unroll
                for (int j = 0; j < 4; ++j)
                    bfr[j] = *(const short8*)(&Bsm[(wn * 64 + j * 16 + l15) * LDK + ks * 32 + lq * 8]);
#pragma unroll
                for (int i = 0; i < 2; ++i)
#pragma unroll
                    for (int j = 0; j < 4; ++j)
                        acc[i][j] = __builtin_amdgcn_mfma_f32_16x16x32_bf16(
                            af[i], bfr[j], acc[i][j], 0, 0, 0);
            }
            __syncthreads();
        }
    }

    // epilogue: lane holds D[m = lq*4+r][n = l15] per 16x16 tile
#pragma unroll
    for (int i = 0; i < 2; ++i) {
        int mbase = m0 + wm * 32 + i * 16 + lq * 4;
#pragma unroll
        for (int j = 0; j < 4; ++j) {
            int n = n0 + wn * 64 + j * 16 + l15;
            if (mode == 9) {
                int b9 = mbase >> 12, hw = mbase & 4095;
                size_t oi = ((size_t)b9 * 256 + n) * 4096 + hw;
                float bn = bias[n];
                float4 xr = *(const float4*)(aux0 + oi);
                float4 res;
                res.x = xr.x + acc[i][j][0] + bn;
                res.y = xr.y + acc[i][j][1] + bn;
                res.z = xr.z + acc[i][j][2] + bn;
                res.w = xr.w + acc[i][j][3] + bn;
                *(float4*)(out + oi) = res;
                continue;
            }
            float bn = bias[n];
#pragma unroll
            for (int r = 0; r < 4; ++r) {
                int m = mbase + r;
                size_t idx = (size_t)m * 256 + n;
                float D = acc[i][j][r] + bn;
                if (mode == 1) {
                    float v = D + pos[(size_t)(m % NTOK) * 256 + n];
                    out[idx] = v; out2[idx] = f2bf(v);
                } else if (mode == 10) {
                    float v = D + pos[(size_t)(m % NTOK) * 256 + n];
                    out2[idx] = f2bf(v);
                } else if (mode == 11) {
                    float r_ = sigm(D);
                    out2[idx] = f2bf(r_ * bf2f(auxb0[idx]) + (1.f - r_) * bf2f(auxb1[idx]));
                } else if (mode == 6) {
                    float l = sigm(D);
                    out2[idx] = f2bf(bf2f(auxb1[idx]) + l * bf2f(auxb0[idx]));
                } else if (mode == 7) {
                    out2[idx] = f2bf(D);
                } else { // 8
                    float e = sigm(D);
                    out2[idx] = f2bf(e * bf2f(auxb0[idx]) + (1.f - e) * bf2f(auxb1[idx]));
                }
            }
        }
    }
}

// ---------------------------------------------------------------------------
// Fused triple-gate GEMM, 64x64 tile (low reg pressure, 2 barriers/k0).
// All three gate B-tiles staged upfront; wave = 32m x 32n, acc[3][2][2].
// Emits a = sigm(-dpre), bb = (1-a)*sigm(wpre)*u, o_bf = bf16(sigm(opre)).
// grid (M/64, 4), block 256.
// ---------------------------------------------------------------------------
__global__ __launch_bounds__(256, 4) void gemm_gates3(
    const u16* __restrict__ A0, const u16* __restrict__ Wg, const float* __restrict__ cf,
    const u16* __restrict__ ubf, float* __restrict__ aF, float* __restrict__ bbF,
    u16* __restrict__ obf, int NTOK)
{
    __shared__ u16 Asm[64 * LDK];
    __shared__ u16 Bsm[3][64 * LDK];
    const int tid = threadIdx.x;
    const int lane = tid & 63, wave = tid >> 6;
    const int wm = wave & 1, wn = wave >> 1;
    const int m0 = blockIdx.x * 64, n0 = blockIdx.y * 64;
    const int l15 = lane & 15, lq = lane >> 4;

    f32x4 acc[3][2][2] = {};

    const int rowA = tid >> 2, kA = (tid & 3) * 16;   // 64 rows, 16 elems each
    const u16* arow = A0 + (size_t)(m0 + rowA) * 256 + kA;
    const u16* wrow = Wg + (size_t)(n0 + rowA) * 256 + kA;

    for (int k0 = 0; k0 < 256; k0 += 64) {
        *(short8*)(&Asm[rowA * LDK + kA])     = *(const short8*)(arow + k0);
        *(short8*)(&Asm[rowA * LDK + kA + 8]) = *(const short8*)(arow + k0 + 8);
#pragma unroll
        for (int ws = 0; ws < 3; ++ws) {
            const u16* wr = wrow + (size_t)ws * 65536 + k0;
            *(short8*)(&Bsm[ws][rowA * LDK + kA])     = *(const short8*)(wr);
            *(short8*)(&Bsm[ws][rowA * LDK + kA + 8]) = *(const short8*)(wr + 8);
        }
        __syncthreads();
#pragma unroll
        for (int ks = 0; ks < 2; ++ks) {
            short8 af[2];
#pragma unroll
            for (int i = 0; i < 2; ++i)
                af[i] = *(const short8*)(&Asm[(wm * 32 + i * 16 + l15) * LDK + ks * 32 + lq * 8]);
#pragma unroll
            for (int ws = 0; ws < 3; ++ws) {
                short8 bfr[2];
#pragma unroll
                for (int j = 0; j < 2; ++j)
                    bfr[j] = *(const short8*)(&Bsm[ws][(wn * 32 + j * 16 + l15) * LDK + ks * 32 + lq * 8]);
#pragma unroll
                for (int i = 0; i < 2; ++i)
#pragma unroll
                    for (int j = 0; j < 2; ++j)
                        acc[ws][i][j] = __builtin_amdgcn_mfma_f32_16x16x32_bf16(
                            af[i], bfr[j], acc[ws][i][j], 0, 0, 0);
            }
        }
        __syncthreads();
    }

#pragma unroll
    for (int i = 0; i < 2; ++i) {
        int mbase = m0 + wm * 32 + i * 16 + lq * 4;
        int bt_ = mbase / NTOK;
#pragma unroll
        for (int j = 0; j < 2; ++j) {
            int n = n0 + wn * 32 + j * 16 + l15;
            float cD = cf[((size_t)0 * B_ + bt_) * C_ + n];
            float cW = cf[((size_t)1 * B_ + bt_) * C_ + n];
            float cO = cf[((size_t)2 * B_ + bt_) * C_ + n];
#pragma unroll
            for (int r = 0; r < 4; ++r) {
                size_t idx = (size_t)(mbase + r) * 256 + n;
                float a_ = sigm(-(acc[0][i][j][r] + cD));
                float g_ = sigm(acc[1][i][j][r] + cW);
                float o_ = sigm(acc[2][i][j][r] + cO);
                float u_ = bf2f(ubf[idx]);
                aF[idx]  = a_;
                bbF[idx] = (1.f - a_) * g_ * u_;
                obf[idx] = f2bf(o_);
            }
        }
    }
}

// ---------------------------------------------------------------------------
// Transpose x [B][C][HW] fp32 -> seq_bf [B][HW][C] bf16.
// grid (HW_/32, C_/32, B), block (32,8)
// ---------------------------------------------------------------------------
__global__ __launch_bounds__(256) void transpose_bf_k(const float* __restrict__ in,
                                                      u16* __restrict__ outb)
{
    __shared__ float t[32][33];
    int b = blockIdx.z;
    int r0 = blockIdx.y * 32, c0 = blockIdx.x * 32;   // r = channel, c = hw
    int tx = threadIdx.x, ty = threadIdx.y;
    const float* ip = in + (size_t)b * HW_ * C_;
    u16* op = outb + (size_t)b * HW_ * C_;
#pragma unroll
    for (int k = 0; k < 32; k += 8)
        t[ty + k][tx] = ip[(size_t)(r0 + ty + k) * HW_ + c0 + tx];
    __syncthreads();
#pragma unroll
    for (int k = 0; k < 32; k += 8)
        op[(size_t)(c0 + ty + k) * C_ + r0 + tx] = f2bf(t[tx][ty + k]);
}

// Fused depthwise 3x3 conv + transpose: x[B][C][HW] -> vseq_bf[B][HW][C] bf16.
__global__ __launch_bounds__(256) void dwconvt2_k(const float* __restrict__ x,
                                                  const float* __restrict__ dww,
                                                  const float* __restrict__ dwb,
                                                  u16* __restrict__ vseq)
{
    __shared__ float t[32][33];
    int b = blockIdx.z;
    int r0 = blockIdx.y * 32, c0 = blockIdx.x * 32;   // r = channel, c = hw
    int tx = threadIdx.x, ty = threadIdx.y;
#pragma unroll
    for (int k = 0; k < 32; k += 8) {
        int ch = r0 + ty + k;
        int hw = c0 + tx;
        int h = hw >> 6, w = hw & 63;
        const float* xp = x + ((size_t)b * C_ + ch) * HW_;
        const float* wp = dww + ch * 9;
        float acc = dwb[ch];
#pragma unroll
        for (int dy = 0; dy < 3; ++dy) {
            int hh = h + dy - 1;
            if (hh < 0 || hh > 63) continue;
#pragma unroll
            for (int dx = 0; dx < 3; ++dx) {
                int ww = w + dx - 1;
                if (ww < 0 || ww > 63) continue;
                acc += xp[hh * 64 + ww] * wp[dy * 3 + dx];
            }
        }
        t[ty + k][tx] = acc;
    }
    __syncthreads();
    u16* op = vseq + (size_t)b * HW_ * C_;
#pragma unroll
    for (int k = 0; k < 32; k += 8)
        op[(size_t)(c0 + ty + k) * C_ + r0 + tx] = f2bf(t[tx][ty + k]);
}

// 4x4 avg pool x -> seqg_bf[B][256][C] bf16.  grid (B, C), block 256 = ghw
__global__ __launch_bounds__(256) void pool_k(const float* __restrict__ x, u16* __restrict__ seqg)
{
    int b = blockIdx.x, c = blockIdx.y, ghw = threadIdx.x;
    int gh = ghw >> 4, gw = ghw & 15;
    const float* xp = x + ((size_t)b * C_ + c) * HW_;
    float s = 0.f;
#pragma unroll
    for (int dy = 0; dy < 4; ++dy)
#pragma unroll
        for (int dx = 0; dx < 4; ++dx)
            s += xp[(gh * 4 + dy) * W_ + gw * 4 + dx];
    seqg[((size_t)b * NG_ + ghw) * C_ + c] = f2bf(s * (1.f / 16.f));
}

// pos_fine [1][256][32][32] -> posF[4096][256] fp32, half-pixel bilinear 2x
__global__ __launch_bounds__(256) void posfine_k(const float* __restrict__ pf, float* __restrict__ posF)
{
    int hw = blockIdx.x, c = threadIdx.x;
    int h = hw >> 6, w = hw & 63;
    float fy = h * 0.5f - 0.25f, fx = w * 0.5f - 0.25f;
    int y0 = (int)floorf(fy); float wy = fy - (float)y0;
    int x0 = (int)floorf(fx); float wx = fx - (float)x0;
    int y0c = min(max(y0, 0), 31), y1c = min(max(y0 + 1, 0), 31);
    int x0c = min(max(x0, 0), 31), x1c = min(max(x0 + 1, 0), 31);
    const float* p = pf + (size_t)c * 1024;
    float v = (1.f - wy) * ((1.f - wx) * p[y0c * 32 + x0c] + wx * p[y0c * 32 + x1c])
            +        wy  * ((1.f - wx) * p[y1c * 32 + x0c] + wx * p[y1c * 32 + x1c]);
    posF[(size_t)hw * C_ + c] = v;
}

// pos_glob -> posG[256][256] fp32: antialiased 2x downsample (4-tap triangle)
__global__ __launch_bounds__(256) void posglob_k(const float* __restrict__ pg, float* __restrict__ posG)
{
    int ghw = blockIdx.x, c = threadIdx.x;
    int gh = ghw >> 4, gw = ghw & 15;
    const float wt[4] = {0.125f, 0.375f, 0.375f, 0.125f};
    float wy[4], wx[4]; int jy[4], jx[4];
    float sy = 0.f, sx = 0.f;
#pragma unroll
    for (int k = 0; k < 4; ++k) {
        jy[k] = 2 * gh - 1 + k; jx[k] = 2 * gw - 1 + k;
        wy[k] = (jy[k] >= 0 && jy[k] < 32) ? wt[k] : 0.f; sy += wy[k];
        wx[k] = (jx[k] >= 0 && jx[k] < 32) ? wt[k] : 0.f; sx += wx[k];
    }
    const float* p = pg + (size_t)c * 1024;
    float acc = 0.f;
#pragma unroll
    for (int ky = 0; ky < 4; ++ky) {
        if (wy[ky] == 0.f) continue;
        float row = 0.f;
#pragma unroll
        for (int kx = 0; kx < 4; ++kx)
            if (wx[kx] != 0.f) row += wx[kx] * p[jy[ky] * 32 + jx[kx]];
        acc += wy[ky] * row;
    }
    posG[(size_t)ghw * C_ + c] = acc / (sy * sx);
}

// y_g[B][256][C] fp32 -> ygs_bf[B][4096][C] bf16: half-pixel bilinear 4x up
__global__ __launch_bounds__(256) void upsample_k(const float* __restrict__ yg, u16* __restrict__ ygs)
{
    int b = blockIdx.x >> 12, hw = blockIdx.x & 4095, c = threadIdx.x;
    int h = hw >> 6, w = hw & 63;
    float fy = h * 0.25f - 0.375f, fx = w * 0.25f - 0.375f;
    int y0 = (int)floorf(fy); float wy = fy - (float)y0;
    int x0 = (int)floorf(fx); float wx = fx - (float)x0;
    int y0c = min(max(y0, 0), 15), y1c = min(max(y0 + 1, 0), 15);
    int x0c = min(max(x0, 0), 15), x1c = min(max(x0 + 1, 0), 15);
    const float* p = yg + (size_t)b * NG_ * C_ + c;
    float v = (1.f - wy) * ((1.f - wx) * p[(y0c * 16 + x0c) * C_] + wx * p[(y0c * 16 + x1c) * C_])
            +        wy  * ((1.f - wx) * p[(y1c * 16 + x0c) * C_] + wx * p[(y1c * 16 + x1c) * C_]);
    ygs[((size_t)b * HW_ + hw) * C_ + c] = f2bf(v);
}

// partial token-mean fp32: grid (B, S), block 256=c
__global__ __launch_bounds__(256) void meanpart_k(const float* __restrict__ u, float* __restrict__ part,
                                                  int Ntok, int chunkLen)
{
    int b = blockIdx.x, s = blockIdx.y, c = threadIdx.x;
    float acc = 0.f;
    for (int i = 0; i < chunkLen; ++i) {
        int t = s * chunkLen + i;
        acc += u[((size_t)b * Ntok + t) * C_ + c];
    }
    part[((size_t)b * gridDim.y + s) * C_ + c] = acc;
}

// partial token-mean bf16 input: grid (B, S), block 256=c
__global__ __launch_bounds__(256) void meanpart_bf_k(const u16* __restrict__ u, float* __restrict__ part,
                                                     int Ntok, int chunkLen)
{
    int b = blockIdx.x, s = blockIdx.y, c = threadIdx.x;
    float acc = 0.f;
    for (int i = 0; i < chunkLen; ++i) {
        int t = s * chunkLen + i;
        acc += bf2f(u[((size_t)b * Ntok + t) * C_ + c]);
    }
    part[((size_t)b * gridDim.y + s) * C_ + c] = acc;
}

// finish mean + LayerNorm over C.  grid (B), block 256
__global__ __launch_bounds__(256) void ln_k(const float* __restrict__ part, int S, float invN,
                                            const float* __restrict__ g, const float* __restrict__ bta,
                                            float* __restrict__ cout)
{
    __shared__ float red[256];
    int c = threadIdx.x, b = blockIdx.x;
    float v = 0.f;
    for (int s = 0; s < S; ++s) v += part[((size_t)b * S + s) * C_ + c];
    v *= invN;
    red[c] = v; __syncthreads();
    for (int st = 128; st > 0; st >>= 1) { if (c < st) red[c] += red[c + st]; __syncthreads(); }
    float m = red[0] * (1.f / 256.f);
    __syncthreads();
    float d = v - m;
    red[c] = d * d; __syncthreads();
    for (int st = 128; st > 0; st >>= 1) { if (c < st) red[c] += red[c + st]; __syncthreads(); }
    float var = red[0] * (1.f / 256.f);
    cout[(size_t)b * C_ + c] = d * rsqrtf(var + 1e-5f) * g[c] + bta[c];
}

// per-batch gate bias rows: cf[gate][b][n] = c[b] @ Wg[256:,:] + bg.  grid (B, 3), block 256
__global__ __launch_bounds__(256) void gatebias_k(const float* __restrict__ cvec,
    const float* __restrict__ Wf, const float* __restrict__ bf,
    const float* __restrict__ Ww, const float* __restrict__ bw,
    const float* __restrict__ Wo, const float* __restrict__ bo,
    float* __restrict__ outb)
{
    int n = threadIdx.x, b = blockIdx.x, gate = blockIdx.y;
    const float* Wm = (gate == 0) ? Wf : ((gate == 1) ? Ww : Wo);
    const float* bi = (gate == 0) ? bf : ((gate == 1) ? bw : bo);
    __shared__ float cs[256];
    cs[n] = cvec[(size_t)b * C_ + n];
    __syncthreads();
    float acc = bi[n];
    for (int k = 0; k < 256; ++k)
        acc += cs[k] * Wm[(size_t)(256 + k) * C_ + n];
    outb[((size_t)gate * B_ + b) * C_ + n] = acc;
}

// ---------------- merged bidirectional chunked scan ----------------------
__global__ __launch_bounds__(256) void scan_p1b(
    const float* __restrict__ a, const float* __restrict__ bb,
    float* __restrict__ AbF, float* __restrict__ BbF,
    float* __restrict__ AbB, float* __restrict__ BbB,
    int Ntok, int nchunk, int both)
{
    int c = threadIdx.x;
    int ch = blockIdx.x % nchunk;
    int b = blockIdx.x / nchunk;
    int CL = Ntok / nchunk;
    size_t base = ((size_t)b * Ntok + (size_t)ch * CL) * C_ + c;
    float sA = 1.f, sB = 0.f;
    for (int i = 0; i < CL; ++i) {
        float av = a[base + (size_t)i * C_];
        sB = av * sB + bb[base + (size_t)i * C_];
        sA *= av;
    }
    size_t o = ((size_t)b * nchunk + ch) * C_ + c;
    AbF[o] = sA; BbF[o] = sB;
    if (both) {
        sA = 1.f; sB = 0.f;
        for (int i = CL - 1; i >= 0; --i) {
            float av = a[base + (size_t)i * C_];
            sB = av * sB + bb[base + (size_t)i * C_];
            sA *= av;
        }
        size_t ob = ((size_t)b * nchunk + (nchunk - 1 - ch)) * C_ + c;
        AbB[ob] = sA; BbB[ob] = sB;
    }
}

__global__ __launch_bounds__(256) void scan_p2b(
    const float* __restrict__ AbF, const float* __restrict__ BbF, float* __restrict__ SbF,
    const float* __restrict__ AbB, const float* __restrict__ BbB, float* __restrict__ SbB,
    int nchunk, int both)
{
    int c = threadIdx.x, b = blockIdx.x;
    float s = 0.f;
    for (int ch = 0; ch < nchunk; ++ch) {
        size_t o = ((size_t)b * nchunk + ch) * C_ + c;
        SbF[o] = s;
        s = AbF[o] * s + BbF[o];
    }
    if (both) {
        s = 0.f;
        for (int ch = 0; ch < nchunk; ++ch) {
            size_t o = ((size_t)b * nchunk + ch) * C_ + c;
            SbB[o] = s;
            s = AbB[o] * s + BbB[o];
        }
    }
}

__global__ __launch_bounds__(256) void scan_p3b(
    const float* __restrict__ a, const float* __restrict__ bb,
    const u16* __restrict__ obf, const u16* __restrict__ ubf,
    const float* __restrict__ SbF, const float* __restrict__ SbB,
    float* __restrict__ yout, u16* __restrict__ ybfF, u16* __restrict__ ybfB,
    int Ntok, int nchunk, int both)
{
    int c = threadIdx.x;
    int ch = blockIdx.x % nchunk;
    int b = blockIdx.x / nchunk;
    int CL = Ntok / nchunk;
    size_t base = ((size_t)b * Ntok + (size_t)ch * CL) * C_ + c;
    float s = SbF[((size_t)b * nchunk + ch) * C_ + c];
    for (int i = 0; i < CL; ++i) {
        size_t idx = base + (size_t)i * C_;
        float av = a[idx];
        s = av * s + bb[idx];
        float ov = bf2f(obf[idx]);
        float y = ov * s + (1.f - ov) * bf2f(ubf[idx]);
        if (yout) yout[idx] = y;
        if (ybfF) ybfF[idx] = f2bf(y);
    }
    if (both) {
        float sb = SbB[((size_t)b * nchunk + (nchunk - 1 - ch)) * C_ + c];
        for (int i = CL - 1; i >= 0; --i) {
            size_t idx = base + (size_t)i * C_;
            float av = a[idx];
            sb = av * sb + bb[idx];
            float ov = bf2f(obf[idx]);
            ybfB[idx] = f2bf(ov * sb + (1.f - ov) * bf2f(ubf[idx]));
        }
    }
}

// ===========================================================================
extern "C" void kernel_launch(void* const* d_in, const int* in_sizes, int n_in,
                              void* d_out, int out_size, void* d_ws, size_t ws_size,
                              hipStream_t stream)
{
    const float* x        = (const float*)d_in[0];
    const float* Wt       = (const float*)d_in[1];
    const float* bt       = (const float*)d_in[2];
    const float* pos_fine = (const float*)d_in[3];
    const float* pos_glob = (const float*)d_in[4];
    const float* ln_g     = (const float*)d_in[5];
    const float* ln_b     = (const float*)d_in[6];
    const float* Wf       = (const float*)d_in[7];
    const float* bf       = (const float*)d_in[8];
    const float* Ww       = (const float*)d_in[9];
    const float* bw       = (const float*)d_in[10];
    const float* Wo       = (const float*)d_in[11];
    const float* bo       = (const float*)d_in[12];
    const float* Wr       = (const float*)d_in[13];
    const float* br       = (const float*)d_in[14];
    const float* Wgi      = (const float*)d_in[15];
    const float* bgi      = (const float*)d_in[16];
    const float* dww      = (const float*)d_in[17];
    const float* dwb      = (const float*)d_in[18];
    const float* Wl       = (const float*)d_in[19];
    const float* bl       = (const float*)d_in[20];
    const float* Wlf      = (const float*)d_in[21];
    const float* blf      = (const float*)d_in[22];
    const float* Wout     = (const float*)d_in[23];
    const float* bout     = (const float*)d_in[24];
    float* out = (float*)d_out;

    float* w = (float*)d_ws;
    const size_t BNC = (size_t)B_ * HW_ * C_;        // 8,388,608 elements
    // fp32 big buffers
    float* bu  = w + 0 * BNC;   // free region -> bwd chunk scratch
    float* ba  = w + 1 * BNC;   // a (fine)
    float* bbb = w + 2 * BNC;   // bb (fine)
    float* bo_ = w + 3 * BNC;   // o_bf lives here as u16
    // bf16 big buffers
    u16* bf1 = (u16*)(w + 4 * BNC);                  // seq_bf -> yf_bf -> z_bf
    u16* bf2 = bf1 + BNC;                            // u_bf -> v_bf
    u16* bf3 = bf2 + BNC;                            // yb_bf -> vseq_bf -> uo_bf
    u16* bf4 = bf3 + BNC;                            // y_bf
    u16* bf5 = bf4 + BNC;                            // ygs_bf (long-lived)
    float* ext = w + 4 * BNC + 5 * (BNC / 2);
    float* posF = ext;  ext += (size_t)HW_ * C_;
    float* posG = ext;  ext += (size_t)NG_ * C_;
    float* part = ext;  ext += (size_t)B_ * 32 * C_;
    float* cln  = ext;  ext += (size_t)B_ * C_;
    float* cf   = ext;  ext += (size_t)3 * B_ * C_;
    float* ug   = ext;  ext += (size_t)B_ * NG_ * C_;
    float* ag   = ext;  ext += (size_t)B_ * NG_ * C_;
    float* bbg  = ext;  ext += (size_t)B_ * NG_ * C_;
    float* ygt  = ext;  ext += (size_t)B_ * NG_ * C_;
    float* chAF = ext;  ext += (size_t)B_ * 64 * C_;
    float* chBF = ext;  ext += (size_t)B_ * 64 * C_;
    float* chSF = ext;  ext += (size_t)B_ * 64 * C_;
    u16* seqg_bf = (u16*)ext;  ext += (size_t)B_ * NG_ * C_ / 2;
    u16* ug_bf   = (u16*)ext;  ext += (size_t)B_ * NG_ * C_ / 2;
    u16* og_bf   = (u16*)ext;  ext += (size_t)B_ * NG_ * C_ / 2;
    u16* Wpre    = (u16*)ext;  // 14 * 65536 bf16 = 1.75 MiB
    // carve bwd scratch + fine o_bf from free fp32 regions
    float* chAB = bu;                       // B*64*C
    float* chBB = bu + (size_t)B_ * 64 * C_;
    float* chSB = bu + (size_t)2 * B_ * 64 * C_;
    u16* obf    = (u16*)bo_;                // fine o gate, bf16

    const dim3 blk256(256);
    const dim3 blkT(32, 8);
    const dim3 gBig(B_ * HW_ / 64, 2);    // 512 x 2 = 1024 blocks
    const dim3 gSml(B_ * NG_ / 64, 2);    // 32 x 2 blocks
    const dim3 gGateF(B_ * HW_ / 64, 4);  // 512 x 4 = 2048 blocks (64x64 tiles)
    const dim3 gGateG(B_ * NG_ / 64, 4);  // 32 x 4 blocks
    const size_t WS = 65536;              // bf16 elems per weight seg
    const float *F0 = nullptr; const u16 *U0 = nullptr;
    float *FW = nullptr; u16 *UW = nullptr;

    // ---- weight prep ------------------------------------------------------
    prepw_k<<<dim3(8, 8, 14), blkT, 0, stream>>>(Wt, Wf, Ww, Wo, Wr, Wgi, Wl, Wlf, Wout, Wpre);

    // ---- fine: seq + u ----------------------------------------------------
    transpose_bf_k<<<dim3(HW_ / 32, C_ / 32, B_), blkT, 0, stream>>>(x, bf1);  // seq_bf
    posfine_k<<<HW_, blk256, 0, stream>>>(pos_fine, posF);
    gemm_bf16<<<gBig, blk256, 0, stream>>>(bf1, U0, U0, 1, Wpre + 0 * WS, bt,
        posF, F0, U0, U0, FW, bf2, HW_, 10);                     // u_bf only

    // ---- global branch ----------------------------------------------------
    pool_k<<<dim3(B_, C_), blk256, 0, stream>>>(x, seqg_bf);
    posglob_k<<<NG_, blk256, 0, stream>>>(pos_glob, posG);
    gemm_bf16<<<gSml, blk256, 0, stream>>>(seqg_bf, U0, U0, 1, Wpre + 0 * WS, bt,
        posG, F0, U0, U0, ug, ug_bf, NG_, 1);                    // u_g fp32 + bf16
    meanpart_k<<<dim3(B_, 8), blk256, 0, stream>>>(ug, part, NG_, 32);
    ln_k<<<B_, blk256, 0, stream>>>(part, 8, 1.f / NG_, ln_g, ln_b, cln);
    gatebias_k<<<dim3(B_, 3), blk256, 0, stream>>>(cln, Wf, bf, Ww, bw, Wo, bo, cf);
    gemm_gates3<<<gGateG, blk256, 0, stream>>>(ug_bf, Wpre + 1 * WS, cf, ug_bf,
        ag, bbg, og_bf, NG_);
    scan_p1b<<<B_ * 16, blk256, 0, stream>>>(ag, bbg, chAF, chBF, FW, FW, NG_, 16, 0);
    scan_p2b<<<B_, blk256, 0, stream>>>(chAF, chBF, chSF, F0, F0, FW, 16, 0);
    scan_p3b<<<B_ * 16, blk256, 0, stream>>>(ag, bbg, og_bf, ug_bf, chSF, F0,
        ygt, UW, UW, NG_, 16, 0);
    upsample_k<<<B_ * HW_, blk256, 0, stream>>>(ygt, bf5);       // ygs_bf

    // ---- fine: gates + merged bidirectional scan --------------------------
    meanpart_bf_k<<<dim3(B_, 32), blk256, 0, stream>>>(bf2, part, HW_, 128);
    ln_k<<<B_, blk256, 0, stream>>>(part, 32, 1.f / HW_, ln_g, ln_b, cln);
    gatebias_k<<<dim3(B_, 3), blk256, 0, stream>>>(cln, Wf, bf, Ww, bw, Wo, bo, cf);
    gemm_gates3<<<gGateF, blk256, 0, stream>>>(bf2, Wpre + 1 * WS, cf, bf2,
        ba, bbb, obf, HW_);
    scan_p1b<<<B_ * 64, blk256, 0, stream>>>(ba, bbb, chAF, chBF, chAB, chBB, HW_, 64, 1);
    scan_p2b<<<B_, blk256, 0, stream>>>(chAF, chBF, chSF, chAB, chBB, chSB, 64, 1);
    scan_p3b<<<B_ * 64, blk256, 0, stream>>>(ba, bbb, obf, bf2, chSF, chSB,
        FW, bf1, bf3, HW_, 64, 1);                               // yf->bf1, yb->bf3

    // ---- rho combine (fused) ----------------------------------------------
    gemm_bf16<<<gBig, blk256, 0, stream>>>(bf2, bf1, bf3, 3, Wpre + 4 * WS, br,
        F0, F0, bf1, bf3, FW, bf4, HW_, 11);                     // y_bf -> bf4

    // ---- lam / z (fused) ---------------------------------------------------
    gemm_bf16<<<gBig, blk256, 0, stream>>>(bf4, bf5, bf2, 3, Wpre + 7 * WS, bgi,
        F0, F0, bf5, bf4, FW, bf1, HW_, 6);                      // z_bf -> bf1

    // ---- local depthwise branch (fused conv+transpose) --------------------
    dwconvt2_k<<<dim3(HW_ / 32, C_ / 32, B_), blkT, 0, stream>>>(x, dww, dwb, bf3); // vseq_bf
    gemm_bf16<<<gBig, blk256, 0, stream>>>(bf3, U0, U0, 1, Wpre + 10 * WS, bl,
        F0, F0, U0, U0, FW, bf2, HW_, 7);                        // v_bf -> bf2
    gemm_bf16<<<gBig, blk256, 0, stream>>>(bf2, bf1, U0, 2, Wpre + 11 * WS, blf,
        F0, F0, bf2, bf1, FW, bf3, HW_, 8);                      // uo_bf -> bf3

    // ---- output projection + residual (fused transpose) -------------------
    gemm_bf16<<<gBig, blk256, 0, stream>>>(bf3, U0, U0, 1, Wpre + 13 * WS, bout,
        F0, x, U0, U0, out, UW, HW_, 9);
}